// Round 2
// baseline (1678.011 us; speedup 1.0000x reference)
//
#include <hip/hip_runtime.h>
#include <hip/hip_bf16.h>
#include <math.h>

// ---------------------------------------------------------------------------
// GCN 2-layer forward, bucket-multisplit pipeline:
//   detect width -> multisplit edges into buckets of 256 dst (LDS-staged,
//   64B-aligned flushes) -> deg/dinv from bucket histograms ->
//   gemm1 (hs1 = x@W1 * dinv) -> agg1 (LDS acc per bucket, +bias+leakyrelu) ->
//   gemm2 (hs2 = out1@W2 * dinv) -> agg2 (LDS acc, +bias+softmax)
// Edge packed as uint32: (src << 8) | (dst & 255); bucket = dst >> 8.
// ---------------------------------------------------------------------------

__device__ __forceinline__ int edge_val(const void* ep, size_t idx, int is64) {
    if (is64) return (int)(((const long long*)ep)[idx]);
    return ((const int*)ep)[idx];
}

// int64 detection: high words of first 64 entries all zero only for int64.
__global__ void detect_width(const unsigned int* __restrict__ ew, int* __restrict__ flag) {
    if (threadIdx.x == 0 && blockIdx.x == 0) {
        int f = 1;
        for (int i = 0; i < 64; ++i)
            if (ew[2 * i + 1] != 0u) { f = 0; break; }
        *flag = f;
    }
}

// Multisplit: LDS ring buffer (32 entries) per bucket, flush 16-entry (64B)
// aligned chunks. Overflow (adversarial inputs only) -> global fallback list.
__global__ __launch_bounds__(256) void binstage(
    const void* __restrict__ edges, int E, const int* __restrict__ flagp,
    unsigned int* __restrict__ ebuf, int cap, int* __restrict__ gfill,
    unsigned long long* __restrict__ ovf, int* __restrict__ govf, int ovfcap, int B) {
    extern __shared__ unsigned int sm[];
    unsigned int* stage = sm;            // B * 32
    int* cnt  = (int*)(sm + (size_t)B * 32);   // B
    int* head = cnt + B;                 // B
    const int tid = threadIdx.x;
    for (int i = tid; i < B; i += 256) { cnt[i] = 0; head[i] = 0; }
    __syncthreads();
    const int is64 = *flagp;
    const long long per = ((long long)E + gridDim.x - 1) / gridDim.x;
    const long long s0 = (long long)blockIdx.x * per;
    const long long s1 = (per + s0 < E) ? (s0 + per) : E;
    for (long long base = s0; base < s1; base += 256) {
        const long long i = base + tid;
        if (i < s1) {
            const int d = edge_val(edges, (size_t)E + i, is64);
            const int s = edge_val(edges, (size_t)i, is64);
            const int b = d >> 8;
            const unsigned int val = ((unsigned int)s << 8) | (unsigned int)(d & 255);
            const int p = atomicAdd(&cnt[b], 1);
            if (p < 32) {
                stage[b * 32 + ((head[b] + p) & 31)] = val;
            } else {
                const int op = atomicAdd(govf, 1);
                if (op < ovfcap) ovf[op] = ((unsigned long long)b << 32) | val;
            }
        }
        __syncthreads();
        for (int bb = tid; bb < B; bb += 256) {
            int c = cnt[bb]; if (c > 32) c = 32;
            int h = head[bb];
            while (c >= 16) {
                const int gpos = atomicAdd(&gfill[bb], 16);
                if (gpos + 16 <= cap) {
                    unsigned int t[16];
#pragma unroll
                    for (int k = 0; k < 16; ++k) t[k] = stage[bb * 32 + ((h + k) & 31)];
                    uint4* d4 = (uint4*)(ebuf + (size_t)bb * cap + gpos);
                    d4[0] = make_uint4(t[0], t[1], t[2], t[3]);
                    d4[1] = make_uint4(t[4], t[5], t[6], t[7]);
                    d4[2] = make_uint4(t[8], t[9], t[10], t[11]);
                    d4[3] = make_uint4(t[12], t[13], t[14], t[15]);
                }
                h = (h + 16) & 31; c -= 16;
            }
            head[bb] = h; cnt[bb] = c;
        }
        __syncthreads();
    }
    // final drain (tails, unaligned, no sentinels)
    for (int bb = tid; bb < B; bb += 256) {
        int c = cnt[bb]; if (c > 32) c = 32;
        const int h = head[bb];
        if (c > 0) {
            const int gpos = atomicAdd(&gfill[bb], c);
            for (int k = 0; k < c; ++k)
                if (gpos + k < cap) ebuf[(size_t)bb * cap + gpos + k] = stage[bb * 32 + ((h + k) & 31)];
        }
    }
}

__global__ void bin_cleanup(const unsigned long long* __restrict__ ovf,
                            const int* __restrict__ govf, unsigned int* __restrict__ ebuf,
                            int cap, int* __restrict__ gfill, int ovfcap) {
    const int m = min(*govf, ovfcap);
    for (int i = blockIdx.x * 256 + threadIdx.x; i < m; i += gridDim.x * 256) {
        const unsigned long long e = ovf[i];
        const int b = (int)(e >> 32);
        const int pos = atomicAdd(&gfill[b], 1);
        if (pos < cap) ebuf[(size_t)b * cap + pos] = (unsigned int)e;
    }
}

// deg/dinv from bucket contents: LDS histogram of 256 dst_local counters.
__global__ __launch_bounds__(256) void degdinv(
    const unsigned int* __restrict__ ebuf, int cap, const int* __restrict__ gfill,
    float* __restrict__ dinv, int n) {
    __shared__ int cnt[256];
    const int b = blockIdx.x;
    cnt[threadIdx.x] = 0;
    __syncthreads();
    const int m = min(gfill[b], cap);
    const unsigned int* eb = ebuf + (size_t)b * cap;
    for (int i = threadIdx.x; i < m; i += 256) atomicAdd(&cnt[eb[i] & 255u], 1);
    __syncthreads();
    const int v = b * 256 + threadIdx.x;
    if (v < n) dinv[v] = rsqrtf((float)cnt[threadIdx.x] + 1.0f);
}

// GEMM1: hs1[v][c] = (sum_k x[v][k]*W1[k][c]) * dinv[v]   (256 -> 64)
__global__ __launch_bounds__(128) void gemm1_kernel(
    const float* __restrict__ x, const float* __restrict__ W1,
    const float* __restrict__ dinv, float* __restrict__ hs1, int n) {
    __shared__ float xs[32 * 132];
    __shared__ float wl[128 * 64];
    const int tid = threadIdx.x;
    const int tj = tid & 15;
    const int ti = tid >> 4;
    const int row0 = blockIdx.x * 32;
    float acc[4][4] = {};
    for (int kt = 0; kt < 2; ++kt) {
        const float4* wsrc = (const float4*)(W1 + kt * 128 * 64);
        float4* wdst = (float4*)wl;
#pragma unroll
        for (int i = 0; i < 16; ++i) wdst[tid + 128 * i] = wsrc[tid + 128 * i];
#pragma unroll
        for (int i = 0; i < 8; ++i) {
            const int flat = tid + 128 * i;
            const int r = flat >> 5;
            const int c4 = flat & 31;
            int gr = row0 + r;
            if (gr >= n) gr = n - 1;
            float4 v = *(const float4*)(x + (size_t)gr * 256 + kt * 128 + c4 * 4);
            *(float4*)(xs + r * 132 + c4 * 4) = v;
        }
        __syncthreads();
#pragma unroll 4
        for (int k = 0; k < 128; ++k) {
            const float4 wv = *(const float4*)(wl + k * 64 + tj * 4);
            float xv[4];
#pragma unroll
            for (int j = 0; j < 4; ++j) xv[j] = xs[(ti * 4 + j) * 132 + k];
#pragma unroll
            for (int j = 0; j < 4; ++j) {
                acc[j][0] += xv[j] * wv.x;
                acc[j][1] += xv[j] * wv.y;
                acc[j][2] += xv[j] * wv.z;
                acc[j][3] += xv[j] * wv.w;
            }
        }
        __syncthreads();
    }
#pragma unroll
    for (int j = 0; j < 4; ++j) {
        const int gr = row0 + ti * 4 + j;
        if (gr < n) {
            const float dv = dinv[gr];
            float4 o;
            o.x = acc[j][0] * dv; o.y = acc[j][1] * dv;
            o.z = acc[j][2] * dv; o.w = acc[j][3] * dv;
            *(float4*)(hs1 + (size_t)gr * 64 + tj * 4) = o;
        }
    }
}

// AGG1: per bucket, LDS acc[256][64]; per edge one coalesced 256B row read +
// conflict-free ds_add. Epilogue fuses self-term, bias, leaky_relu.
__global__ __launch_bounds__(512) void agg1_kernel(
    const unsigned int* __restrict__ ebuf, int cap, const int* __restrict__ gfill,
    const float* __restrict__ hs1, const float* __restrict__ dinv,
    const float* __restrict__ b1, float* __restrict__ out1, int n) {
    extern __shared__ float acc[];  // 256*64 floats = 64KB
    const int tid = threadIdx.x;
    const float4 z4 = make_float4(0.f, 0.f, 0.f, 0.f);
#pragma unroll
    for (int i = 0; i < 8; ++i) ((float4*)acc)[tid + 512 * i] = z4;
    __syncthreads();
    const int b = blockIdx.x;
    const int m = min(gfill[b], cap);
    const unsigned int* eb = ebuf + (size_t)b * cap;
    const int lane = tid & 63;
    const int wv = tid >> 6;  // 8 waves
    for (int base = wv * 64; base < m; base += 512) {
        const int idx = base + lane;
        const unsigned int val = (idx < m) ? eb[idx] : 0u;
        const int c = min(64, m - base);
        int j = 0;
        for (; j + 4 <= c; j += 4) {
            const unsigned int v0 = __shfl(val, j + 0);
            const unsigned int v1 = __shfl(val, j + 1);
            const unsigned int v2 = __shfl(val, j + 2);
            const unsigned int v3 = __shfl(val, j + 3);
            const float x0 = hs1[(size_t)(v0 >> 8) * 64 + lane];
            const float x1 = hs1[(size_t)(v1 >> 8) * 64 + lane];
            const float x2 = hs1[(size_t)(v2 >> 8) * 64 + lane];
            const float x3 = hs1[(size_t)(v3 >> 8) * 64 + lane];
            unsafeAtomicAdd(&acc[(v0 & 255u) * 64 + lane], x0);
            unsafeAtomicAdd(&acc[(v1 & 255u) * 64 + lane], x1);
            unsafeAtomicAdd(&acc[(v2 & 255u) * 64 + lane], x2);
            unsafeAtomicAdd(&acc[(v3 & 255u) * 64 + lane], x3);
        }
        for (; j < c; ++j) {
            const unsigned int v = __shfl(val, j);
            const float x = hs1[(size_t)(v >> 8) * 64 + lane];
            unsafeAtomicAdd(&acc[(v & 255u) * 64 + lane], x);
        }
    }
    __syncthreads();
    for (int i = tid; i < 256 * 64; i += 512) {
        const int dl = i >> 6, cc = i & 63;
        const int v = b * 256 + dl;
        if (v < n) {
            const float dv = dinv[v];
            const float r = dv * acc[i] + hs1[(size_t)v * 64 + cc] * dv + b1[cc];
            out1[(size_t)v * 64 + cc] = r > 0.f ? r : 0.01f * r;
        }
    }
}

// GEMM2: hs2[v][c] = (sum_k out1[v][k]*W2[k][c]) * dinv[v]   (64 -> 4)
__global__ __launch_bounds__(256) void gemm2_kernel(
    const float* __restrict__ out1, const float* __restrict__ W2,
    const float* __restrict__ dinv, float* __restrict__ hs2, int n) {
    __shared__ float4 wl[64];
    const int tid = threadIdx.x;
    if (tid < 64) wl[tid] = *(const float4*)(W2 + tid * 4);
    __syncthreads();
    const int row = blockIdx.x * 256 + tid;
    if (row >= n) return;
    const float4* xr = (const float4*)(out1 + (size_t)row * 64);
    float ax = 0.f, ay = 0.f, az = 0.f, aw = 0.f;
#pragma unroll
    for (int k4 = 0; k4 < 16; ++k4) {
        const float4 xv = xr[k4];
        const float4 w0 = wl[k4 * 4 + 0], w1 = wl[k4 * 4 + 1];
        const float4 w2 = wl[k4 * 4 + 2], w3 = wl[k4 * 4 + 3];
        ax += xv.x * w0.x + xv.y * w1.x + xv.z * w2.x + xv.w * w3.x;
        ay += xv.x * w0.y + xv.y * w1.y + xv.z * w2.y + xv.w * w3.y;
        az += xv.x * w0.z + xv.y * w1.z + xv.z * w2.z + xv.w * w3.z;
        aw += xv.x * w0.w + xv.y * w1.w + xv.z * w2.w + xv.w * w3.w;
    }
    const float dv = dinv[row];
    float4 o; o.x = ax * dv; o.y = ay * dv; o.z = az * dv; o.w = aw * dv;
    *(float4*)(hs2 + (size_t)row * 4) = o;
}

// AGG2 + softmax: per bucket, LDS acc[256][4]; 16 edges x 4 cols per wave-step.
__global__ __launch_bounds__(512) void agg2_kernel(
    const unsigned int* __restrict__ ebuf, int cap, const int* __restrict__ gfill,
    const float* __restrict__ hs2, const float* __restrict__ dinv,
    const float* __restrict__ b2, float* __restrict__ out, int n) {
    __shared__ float acc[256 * 4];
    const int tid = threadIdx.x;
    if (tid < 256) ((float4*)acc)[tid] = make_float4(0.f, 0.f, 0.f, 0.f);
    __syncthreads();
    const int b = blockIdx.x;
    const int m = min(gfill[b], cap);
    const unsigned int* eb = ebuf + (size_t)b * cap;
    const int lane = tid & 63;
    const int wv = tid >> 6;
    const int c = lane & 3;
    const int sub = lane >> 2;  // 0..15
    for (int base = wv * 64; base < m; base += 512) {
        const int idx = base + lane;
        const unsigned int val = (idx < m) ? eb[idx] : 0u;
        const int cend = min(64, m - base);
        for (int j = 0; j < cend; j += 16) {
            const unsigned int v = __shfl(val, j + sub);
            if (j + sub < cend) {
                unsafeAtomicAdd(&acc[(v & 255u) * 4 + c], hs2[(size_t)(v >> 8) * 4 + c]);
            }
        }
    }
    __syncthreads();
    if (tid < 256) {
        const int v = b * 256 + tid;
        if (v < n) {
            const float dv = dinv[v];
            const float4 h = ((const float4*)hs2)[v];
            float e0 = dv * acc[tid * 4 + 0] + h.x * dv + b2[0];
            float e1 = dv * acc[tid * 4 + 1] + h.y * dv + b2[1];
            float e2 = dv * acc[tid * 4 + 2] + h.z * dv + b2[2];
            float e3 = dv * acc[tid * 4 + 3] + h.w * dv + b2[3];
            const float mx = fmaxf(fmaxf(e0, e1), fmaxf(e2, e3));
            e0 = __expf(e0 - mx); e1 = __expf(e1 - mx);
            e2 = __expf(e2 - mx); e3 = __expf(e3 - mx);
            const float inv = 1.0f / (e0 + e1 + e2 + e3);
            float4 o; o.x = e0 * inv; o.y = e1 * inv; o.z = e2 * inv; o.w = e3 * inv;
            ((float4*)out)[v] = o;
        }
    }
}

extern "C" void kernel_launch(void* const* d_in, const int* in_sizes, int n_in,
                              void* d_out, int out_size, void* d_ws, size_t ws_size,
                              hipStream_t stream) {
    const float* x  = (const float*)d_in[0];
    const void*  ei = d_in[1];
    const float* W1 = (const float*)d_in[2];
    const float* b1 = (const float*)d_in[3];
    const float* W2 = (const float*)d_in[4];
    const float* b2 = (const float*)d_in[5];
    const int n = in_sizes[0] / 256;
    const int E = in_sizes[1] / 2;
    const int B = (n + 255) / 256;

    char* ws = (char*)d_ws;
    size_t off = 0;
    auto alloc = [&](size_t bytes) -> void* {
        void* p = ws + off;
        off += (bytes + 255) & ~(size_t)255;
        return p;
    };
    int*   flag  = (int*)alloc(sizeof(int) * 64);
    int*   gfill = (int*)alloc(sizeof(int) * (B + 1));  // [B]=govf
    float* dinv  = (float*)alloc(sizeof(float) * n);
    float* hs1   = (float*)alloc(sizeof(float) * (size_t)n * 64);
    float* out1  = (float*)alloc(sizeof(float) * (size_t)n * 64);
    float* hs2   = (float*)alloc(sizeof(float) * (size_t)n * 4);
    // bucket buffer: pick CAP that fits, leaving >=1MB for overflow list
    int CAP = 16384;
    {
        size_t rem = (ws_size > off) ? (ws_size - off) : 0;
        while (CAP > 9216 && (size_t)B * CAP * 4 + (1u << 20) > rem) CAP -= 1024;
    }
    unsigned int* ebuf = (unsigned int*)alloc(sizeof(unsigned int) * (size_t)B * CAP);
    size_t rem2 = (ws_size > off) ? (ws_size - off) : 0;
    int ovfcap = (int)((rem2 / 8 < (size_t)E) ? rem2 / 8 : (size_t)E);
    unsigned long long* ovf = (unsigned long long*)alloc(sizeof(unsigned long long) * (size_t)ovfcap);
    int* govf = gfill + B;
    (void)n_in; (void)out_size;

    hipMemsetAsync(gfill, 0, sizeof(int) * (B + 1), stream);
    detect_width<<<1, 64, 0, stream>>>((const unsigned int*)ei, flag);
    const size_t smem_bin = (size_t)(B * 32 + 2 * B) * sizeof(unsigned int);
    binstage<<<512, 256, smem_bin, stream>>>(ei, E, flag, ebuf, CAP, gfill, ovf, govf, ovfcap, B);
    bin_cleanup<<<16, 256, 0, stream>>>(ovf, govf, ebuf, CAP, gfill, ovfcap);
    degdinv<<<B, 256, 0, stream>>>(ebuf, CAP, gfill, dinv, n);
    gemm1_kernel<<<(n + 31) / 32, 128, 0, stream>>>(x, W1, dinv, hs1, n);
    agg1_kernel<<<B, 512, 256 * 64 * sizeof(float), stream>>>(ebuf, CAP, gfill, hs1, dinv, b1, out1, n);
    gemm2_kernel<<<(n + 255) / 256, 256, 0, stream>>>(out1, W2, dinv, hs2, n);
    agg2_kernel<<<B, 512, 0, stream>>>(ebuf, CAP, gfill, hs2, dinv, b2, (float*)d_out, n);
}

// Round 3
// 303.545 us; speedup vs baseline: 5.5281x; 5.5281x over previous
//
#include <hip/hip_runtime.h>
#include <hip/hip_bf16.h>
#include <math.h>

// ---------------------------------------------------------------------------
// GCN 2-layer forward. Pipeline:
//   detect width -> binstage (multisplit edges into buckets of 256 dst,
//   LDS-staged 64B flushes) -> bucket_base (scan bucket sizes) ->
//   bucket_csr (per-bucket counting sort -> col_src CSR + row_ptr + dinv) ->
//   gemm1 (hs1 = x@W1 * dinv) -> agg1 (wave per node, CSR gather) ->
//   gemm2 (hs2 = out1@W2 * dinv) -> agg2 (wave per node + softmax)
// Edge packed as uint32: (src << 8) | (dst & 255); bucket = dst >> 8.
// ---------------------------------------------------------------------------

__device__ __forceinline__ int edge_val(const void* ep, size_t idx, int is64) {
    if (is64) return (int)(((const long long*)ep)[idx]);
    return ((const int*)ep)[idx];
}

__global__ void detect_width(const unsigned int* __restrict__ ew, int* __restrict__ flag) {
    if (threadIdx.x == 0 && blockIdx.x == 0) {
        int f = 1;
        for (int i = 0; i < 64; ++i)
            if (ew[2 * i + 1] != 0u) { f = 0; break; }
        *flag = f;
    }
}

// Multisplit: LDS ring buffer (32 entries) per bucket, flush 16-entry (64B)
// aligned chunks. Rare overflow -> global fallback list.
__global__ __launch_bounds__(256) void binstage(
    const void* __restrict__ edges, int E, const int* __restrict__ flagp,
    unsigned int* __restrict__ ebuf, int cap, int* __restrict__ gfill,
    unsigned long long* __restrict__ ovf, int* __restrict__ govf, int ovfcap, int B) {
    extern __shared__ unsigned int sm[];
    unsigned int* stage = sm;                  // B * 32
    int* cnt  = (int*)(sm + (size_t)B * 32);   // B
    int* head = cnt + B;                       // B
    const int tid = threadIdx.x;
    for (int i = tid; i < B; i += 256) { cnt[i] = 0; head[i] = 0; }
    __syncthreads();
    const int is64 = *flagp;
    const long long per = ((long long)E + gridDim.x - 1) / gridDim.x;
    const long long s0 = (long long)blockIdx.x * per;
    const long long s1 = (per + s0 < E) ? (s0 + per) : E;
    for (long long base = s0; base < s1; base += 256) {
        const long long i = base + tid;
        if (i < s1) {
            const int d = edge_val(edges, (size_t)E + i, is64);
            const int s = edge_val(edges, (size_t)i, is64);
            const int b = d >> 8;
            const unsigned int val = ((unsigned int)s << 8) | (unsigned int)(d & 255);
            const int p = atomicAdd(&cnt[b], 1);
            if (p < 32) {
                stage[b * 32 + ((head[b] + p) & 31)] = val;
            } else {
                const int op = atomicAdd(govf, 1);
                if (op < ovfcap) ovf[op] = ((unsigned long long)b << 32) | val;
            }
        }
        __syncthreads();
        for (int bb = tid; bb < B; bb += 256) {
            int c = cnt[bb]; if (c > 32) c = 32;
            int h = head[bb];
            while (c >= 16) {
                const int gpos = atomicAdd(&gfill[bb], 16);
                if (gpos + 16 <= cap) {
                    unsigned int t[16];
#pragma unroll
                    for (int k = 0; k < 16; ++k) t[k] = stage[bb * 32 + ((h + k) & 31)];
                    uint4* d4 = (uint4*)(ebuf + (size_t)bb * cap + gpos);
                    d4[0] = make_uint4(t[0], t[1], t[2], t[3]);
                    d4[1] = make_uint4(t[4], t[5], t[6], t[7]);
                    d4[2] = make_uint4(t[8], t[9], t[10], t[11]);
                    d4[3] = make_uint4(t[12], t[13], t[14], t[15]);
                }
                h = (h + 16) & 31; c -= 16;
            }
            head[bb] = h; cnt[bb] = c;
        }
        __syncthreads();
    }
    for (int bb = tid; bb < B; bb += 256) {
        int c = cnt[bb]; if (c > 32) c = 32;
        const int h = head[bb];
        if (c > 0) {
            const int gpos = atomicAdd(&gfill[bb], c);
            for (int k = 0; k < c; ++k)
                if (gpos + k < cap) ebuf[(size_t)bb * cap + gpos + k] = stage[bb * 32 + ((h + k) & 31)];
        }
    }
}

__global__ void bin_cleanup(const unsigned long long* __restrict__ ovf,
                            const int* __restrict__ govf, unsigned int* __restrict__ ebuf,
                            int cap, int* __restrict__ gfill, int ovfcap) {
    const int m = min(*govf, ovfcap);
    for (int i = blockIdx.x * 256 + threadIdx.x; i < m; i += gridDim.x * 256) {
        const unsigned long long e = ovf[i];
        const int b = (int)(e >> 32);
        const int pos = atomicAdd(&gfill[b], 1);
        if (pos < cap) ebuf[(size_t)b * cap + pos] = (unsigned int)e;
    }
}

// Exclusive scan of (clamped) bucket sizes -> bbase; row_ptr[n] = total.
// Single block, 512 threads; B <= 512.
__global__ __launch_bounds__(512) void bucket_base(
    const int* __restrict__ gfill, int* __restrict__ bbase,
    int* __restrict__ row_ptr, int B, int cap, int n) {
    __shared__ int sm[512];
    const int tid = threadIdx.x;
    const int v = (tid < B) ? min(gfill[tid], cap) : 0;
    sm[tid] = v;
    __syncthreads();
    for (int off = 1; off < 512; off <<= 1) {
        int val = (tid >= off) ? sm[tid - off] : 0;
        __syncthreads();
        sm[tid] += val;
        __syncthreads();
    }
    if (tid < B) bbase[tid] = sm[tid] - v;
    if (tid == B - 1) row_ptr[n] = sm[tid];
}

// Per-bucket counting sort: histogram -> LDS scan -> scatter src into
// col_src[bbase[b] .. bbase[b]+m). Also writes row_ptr and dinv.
__global__ __launch_bounds__(512) void bucket_csr(
    const unsigned int* __restrict__ ebuf, int cap, const int* __restrict__ gfill,
    const int* __restrict__ bbase, int* __restrict__ row_ptr,
    float* __restrict__ dinv, int* __restrict__ col_src, int n) {
    __shared__ int hist[256];
    __shared__ int scn[256];
    __shared__ int fill[256];
    const int tid = threadIdx.x;
    const int b = blockIdx.x;
    if (tid < 256) hist[tid] = 0;
    __syncthreads();
    const int m = min(gfill[b], cap);
    const unsigned int* eb = ebuf + (size_t)b * cap;
    for (int i = tid; i < m; i += 512) atomicAdd(&hist[eb[i] & 255u], 1);
    __syncthreads();
    if (tid < 256) scn[tid] = hist[tid];
    __syncthreads();
    for (int off = 1; off < 256; off <<= 1) {
        int val = 0;
        if (tid < 256 && tid >= off) val = scn[tid - off];
        __syncthreads();
        if (tid < 256) scn[tid] += val;
        __syncthreads();
    }
    if (tid < 256) {
        const int excl = scn[tid] - hist[tid];
        fill[tid] = excl;
        const int v = b * 256 + tid;
        if (v < n) {
            row_ptr[v] = bbase[b] + excl;
            dinv[v] = rsqrtf((float)hist[tid] + 1.0f);
        }
    }
    __syncthreads();
    const int base = bbase[b];
    for (int i = tid; i < m; i += 512) {
        const unsigned int e = eb[i];
        const int p = atomicAdd(&fill[e & 255u], 1);
        col_src[base + p] = (int)(e >> 8);
    }
}

// GEMM1: hs1[v][c] = (sum_k x[v][k]*W1[k][c]) * dinv[v]   (256 -> 64)
__global__ __launch_bounds__(128) void gemm1_kernel(
    const float* __restrict__ x, const float* __restrict__ W1,
    const float* __restrict__ dinv, float* __restrict__ hs1, int n) {
    __shared__ float xs[32 * 132];
    __shared__ float wl[128 * 64];
    const int tid = threadIdx.x;
    const int tj = tid & 15;
    const int ti = tid >> 4;
    const int row0 = blockIdx.x * 32;
    float acc[4][4] = {};
    for (int kt = 0; kt < 2; ++kt) {
        const float4* wsrc = (const float4*)(W1 + kt * 128 * 64);
        float4* wdst = (float4*)wl;
#pragma unroll
        for (int i = 0; i < 16; ++i) wdst[tid + 128 * i] = wsrc[tid + 128 * i];
#pragma unroll
        for (int i = 0; i < 8; ++i) {
            const int flat = tid + 128 * i;
            const int r = flat >> 5;
            const int c4 = flat & 31;
            int gr = row0 + r;
            if (gr >= n) gr = n - 1;
            float4 v = *(const float4*)(x + (size_t)gr * 256 + kt * 128 + c4 * 4);
            *(float4*)(xs + r * 132 + c4 * 4) = v;
        }
        __syncthreads();
#pragma unroll 4
        for (int k = 0; k < 128; ++k) {
            const float4 wv = *(const float4*)(wl + k * 64 + tj * 4);
            float xv[4];
#pragma unroll
            for (int j = 0; j < 4; ++j) xv[j] = xs[(ti * 4 + j) * 132 + k];
#pragma unroll
            for (int j = 0; j < 4; ++j) {
                acc[j][0] += xv[j] * wv.x;
                acc[j][1] += xv[j] * wv.y;
                acc[j][2] += xv[j] * wv.z;
                acc[j][3] += xv[j] * wv.w;
            }
        }
        __syncthreads();
    }
#pragma unroll
    for (int j = 0; j < 4; ++j) {
        const int gr = row0 + ti * 4 + j;
        if (gr < n) {
            const float dv = dinv[gr];
            float4 o;
            o.x = acc[j][0] * dv; o.y = acc[j][1] * dv;
            o.z = acc[j][2] * dv; o.w = acc[j][3] * dv;
            *(float4*)(hs1 + (size_t)gr * 64 + tj * 4) = o;
        }
    }
}

// AGG1: wave per node, lane = column; 8-deep gather unroll for MLP.
__global__ __launch_bounds__(256) void agg1_kernel(
    const int* __restrict__ row_ptr, const int* __restrict__ col_src,
    const float* __restrict__ hs1, const float* __restrict__ dinv,
    const float* __restrict__ b1, float* __restrict__ out1, int n) {
    const int lane = threadIdx.x & 63;
    int v = blockIdx.x * 4 + (threadIdx.x >> 6);
    v = __builtin_amdgcn_readfirstlane(v);
    if (v >= n) return;
    const int rs = row_ptr[v];
    const int re = row_ptr[v + 1];
    float a0 = 0.f, a1 = 0.f, a2 = 0.f, a3 = 0.f;
    int e = rs;
    for (; e + 8 <= re; e += 8) {
        const int s0 = col_src[e],     s1 = col_src[e + 1];
        const int s2 = col_src[e + 2], s3 = col_src[e + 3];
        const int s4 = col_src[e + 4], s5 = col_src[e + 5];
        const int s6 = col_src[e + 6], s7 = col_src[e + 7];
        const float x0 = hs1[(size_t)s0 * 64 + lane];
        const float x1 = hs1[(size_t)s1 * 64 + lane];
        const float x2 = hs1[(size_t)s2 * 64 + lane];
        const float x3 = hs1[(size_t)s3 * 64 + lane];
        const float x4 = hs1[(size_t)s4 * 64 + lane];
        const float x5 = hs1[(size_t)s5 * 64 + lane];
        const float x6 = hs1[(size_t)s6 * 64 + lane];
        const float x7 = hs1[(size_t)s7 * 64 + lane];
        a0 += x0; a1 += x1; a2 += x2; a3 += x3;
        a0 += x4; a1 += x5; a2 += x6; a3 += x7;
    }
    for (; e + 4 <= re; e += 4) {
        const int s0 = col_src[e], s1 = col_src[e + 1], s2 = col_src[e + 2], s3 = col_src[e + 3];
        a0 += hs1[(size_t)s0 * 64 + lane];
        a1 += hs1[(size_t)s1 * 64 + lane];
        a2 += hs1[(size_t)s2 * 64 + lane];
        a3 += hs1[(size_t)s3 * 64 + lane];
    }
    for (; e < re; ++e) a0 += hs1[(size_t)col_src[e] * 64 + lane];
    const float acc = (a0 + a1) + (a2 + a3);
    const float res = dinv[v] * (acc + hs1[(size_t)v * 64 + lane]) + b1[lane];
    out1[(size_t)v * 64 + lane] = res > 0.f ? res : 0.01f * res;
}

// GEMM2: hs2[v][c] = (sum_k out1[v][k]*W2[k][c]) * dinv[v]   (64 -> 4)
__global__ __launch_bounds__(256) void gemm2_kernel(
    const float* __restrict__ out1, const float* __restrict__ W2,
    const float* __restrict__ dinv, float* __restrict__ hs2, int n) {
    __shared__ float4 wl[64];
    const int tid = threadIdx.x;
    if (tid < 64) wl[tid] = *(const float4*)(W2 + tid * 4);
    __syncthreads();
    const int row = blockIdx.x * 256 + tid;
    if (row >= n) return;
    const float4* xr = (const float4*)(out1 + (size_t)row * 64);
    float ax = 0.f, ay = 0.f, az = 0.f, aw = 0.f;
#pragma unroll
    for (int k4 = 0; k4 < 16; ++k4) {
        const float4 xv = xr[k4];
        const float4 w0 = wl[k4 * 4 + 0], w1 = wl[k4 * 4 + 1];
        const float4 w2 = wl[k4 * 4 + 2], w3 = wl[k4 * 4 + 3];
        ax += xv.x * w0.x + xv.y * w1.x + xv.z * w2.x + xv.w * w3.x;
        ay += xv.x * w0.y + xv.y * w1.y + xv.z * w2.y + xv.w * w3.y;
        az += xv.x * w0.z + xv.y * w1.z + xv.z * w2.z + xv.w * w3.z;
        aw += xv.x * w0.w + xv.y * w1.w + xv.z * w2.w + xv.w * w3.w;
    }
    const float dv = dinv[row];
    float4 o; o.x = ax * dv; o.y = ay * dv; o.z = az * dv; o.w = aw * dv;
    *(float4*)(hs2 + (size_t)row * 4) = o;
}

// AGG2 + softmax: wave per node; lane -> (edge slot = lane>>2, col = lane&3)
__global__ __launch_bounds__(256) void agg2_kernel(
    const int* __restrict__ row_ptr, const int* __restrict__ col_src,
    const float* __restrict__ hs2, const float* __restrict__ dinv,
    const float* __restrict__ b2, float* __restrict__ out, int n) {
    const int lane = threadIdx.x & 63;
    int v = blockIdx.x * 4 + (threadIdx.x >> 6);
    v = __builtin_amdgcn_readfirstlane(v);
    if (v >= n) return;
    const int c = lane & 3;
    const int ei = lane >> 2;
    const int rs = row_ptr[v];
    const int re = row_ptr[v + 1];
    float acc = 0.f;
    for (int e0 = rs; e0 < re; e0 += 16) {
        const int e = e0 + ei;
        if (e < re) {
            const int s = col_src[e];
            acc += hs2[(size_t)s * 4 + c];
        }
    }
    acc += __shfl_xor(acc, 4);
    acc += __shfl_xor(acc, 8);
    acc += __shfl_xor(acc, 16);
    acc += __shfl_xor(acc, 32);
    const float val = dinv[v] * (acc + hs2[(size_t)v * 4 + c]) + b2[c];
    float m = fmaxf(val, __shfl_xor(val, 1));
    m = fmaxf(m, __shfl_xor(m, 2));
    const float ex = __expf(val - m);
    float s = ex + __shfl_xor(ex, 1);
    s += __shfl_xor(s, 2);
    if (lane < 4) out[(size_t)v * 4 + c] = ex / s;
}

extern "C" void kernel_launch(void* const* d_in, const int* in_sizes, int n_in,
                              void* d_out, int out_size, void* d_ws, size_t ws_size,
                              hipStream_t stream) {
    const float* x  = (const float*)d_in[0];
    const void*  ei = d_in[1];
    const float* W1 = (const float*)d_in[2];
    const float* b1 = (const float*)d_in[3];
    const float* W2 = (const float*)d_in[4];
    const float* b2 = (const float*)d_in[5];
    const int n = in_sizes[0] / 256;
    const int E = in_sizes[1] / 2;
    const int B = (n + 255) / 256;

    char* ws = (char*)d_ws;
    size_t off = 0;
    auto alloc = [&](size_t bytes) -> void* {
        void* p = ws + off;
        off += (bytes + 255) & ~(size_t)255;
        return p;
    };
    int*   flag    = (int*)alloc(sizeof(int) * 64);
    int*   gfill   = (int*)alloc(sizeof(int) * (B + 1));  // [B]=govf
    int*   bbase   = (int*)alloc(sizeof(int) * B);
    int*   row_ptr = (int*)alloc(sizeof(int) * (n + 1));
    int*   col_src = (int*)alloc(sizeof(int) * (size_t)E);
    float* dinv    = (float*)alloc(sizeof(float) * n);
    float* hs1     = (float*)alloc(sizeof(float) * (size_t)n * 64);
    float* out1    = (float*)alloc(sizeof(float) * (size_t)n * 64);
    float* hs2     = (float*)alloc(sizeof(float) * (size_t)n * 4);
    int CAP = 16384;
    {
        size_t rem = (ws_size > off) ? (ws_size - off) : 0;
        while (CAP > 9216 && (size_t)B * CAP * 4 + (1u << 20) > rem) CAP -= 1024;
    }
    unsigned int* ebuf = (unsigned int*)alloc(sizeof(unsigned int) * (size_t)B * CAP);
    size_t rem2 = (ws_size > off) ? (ws_size - off) : 0;
    int ovfcap = (int)((rem2 / 8 < (size_t)E) ? rem2 / 8 : (size_t)E);
    unsigned long long* ovf = (unsigned long long*)alloc(sizeof(unsigned long long) * (size_t)ovfcap);
    int* govf = gfill + B;
    (void)n_in; (void)out_size;

    hipMemsetAsync(gfill, 0, sizeof(int) * (B + 1), stream);
    detect_width<<<1, 64, 0, stream>>>((const unsigned int*)ei, flag);
    const size_t smem_bin = (size_t)(B * 32 + 2 * B) * sizeof(unsigned int);
    binstage<<<1024, 256, smem_bin, stream>>>(ei, E, flag, ebuf, CAP, gfill, ovf, govf, ovfcap, B);
    bin_cleanup<<<16, 256, 0, stream>>>(ovf, govf, ebuf, CAP, gfill, ovfcap);
    bucket_base<<<1, 512, 0, stream>>>(gfill, bbase, row_ptr, B, CAP, n);
    bucket_csr<<<B, 512, 0, stream>>>(ebuf, CAP, gfill, bbase, row_ptr, dinv, col_src, n);
    gemm1_kernel<<<(n + 31) / 32, 128, 0, stream>>>(x, W1, dinv, hs1, n);
    agg1_kernel<<<(n + 3) / 4, 256, 0, stream>>>(row_ptr, col_src, hs1, dinv, b1, out1, n);
    gemm2_kernel<<<(n + 255) / 256, 256, 0, stream>>>(out1, W2, dinv, hs2, n);
    agg2_kernel<<<(n + 3) / 4, 256, 0, stream>>>(row_ptr, col_src, hs2, dinv, b2, (float*)d_out, n);
}

// Round 4
// 263.900 us; speedup vs baseline: 6.3585x; 1.1502x over previous
//
#include <hip/hip_runtime.h>
#include <hip/hip_bf16.h>
#include <math.h>

// ---------------------------------------------------------------------------
// GCN 2-layer forward. Pipeline:
//   detect width -> binstage (multisplit edges into buckets of 256 dst) ->
//   bucket_base (scan) -> bucket_csr (counting sort -> CSR + dinv) ->
//   gemm1 (hs1b = bf16((x@W1) * dinv)) -> agg1 (wave/node, bf16x4 gather) ->
//   gemm2 (hs2 = out1@W2 * dinv) -> agg2 (wave/node + softmax)
// Edge packed as uint32: (src << 8) | (dst & 255); bucket = dst >> 8.
// hs1 kept in bf16: halves the random-gather fabric traffic in agg1 (the top
// dispatch, 368MB FETCH @3.8TB/s in round 3); error budget ~5e-4 vs 5.6e-3.
// ---------------------------------------------------------------------------

__device__ __forceinline__ int edge_val(const void* ep, size_t idx, int is64) {
    if (is64) return (int)(((const long long*)ep)[idx]);
    return ((const int*)ep)[idx];
}

__device__ __forceinline__ unsigned short f2bf(float f) {  // RNE
    unsigned int u = __float_as_uint(f);
    return (unsigned short)((u + 0x7FFFu + ((u >> 16) & 1u)) >> 16);
}
__device__ __forceinline__ float bf2f(unsigned short b) {
    return __uint_as_float((unsigned int)b << 16);
}

__global__ void detect_width(const unsigned int* __restrict__ ew, int* __restrict__ flag) {
    if (threadIdx.x == 0 && blockIdx.x == 0) {
        int f = 1;
        for (int i = 0; i < 64; ++i)
            if (ew[2 * i + 1] != 0u) { f = 0; break; }
        *flag = f;
    }
}

// Multisplit: LDS ring buffer (32 entries) per bucket, flush 16-entry (64B)
// aligned chunks. Rare overflow -> global fallback list.
__global__ __launch_bounds__(256) void binstage(
    const void* __restrict__ edges, int E, const int* __restrict__ flagp,
    unsigned int* __restrict__ ebuf, int cap, int* __restrict__ gfill,
    unsigned long long* __restrict__ ovf, int* __restrict__ govf, int ovfcap, int B) {
    extern __shared__ unsigned int sm[];
    unsigned int* stage = sm;                  // B * 32
    int* cnt  = (int*)(sm + (size_t)B * 32);   // B
    int* head = cnt + B;                       // B
    const int tid = threadIdx.x;
    for (int i = tid; i < B; i += 256) { cnt[i] = 0; head[i] = 0; }
    __syncthreads();
    const int is64 = *flagp;
    const long long per = ((long long)E + gridDim.x - 1) / gridDim.x;
    const long long s0 = (long long)blockIdx.x * per;
    const long long s1 = (per + s0 < E) ? (s0 + per) : E;
    for (long long base = s0; base < s1; base += 256) {
        const long long i = base + tid;
        if (i < s1) {
            const int d = edge_val(edges, (size_t)E + i, is64);
            const int s = edge_val(edges, (size_t)i, is64);
            const int b = d >> 8;
            const unsigned int val = ((unsigned int)s << 8) | (unsigned int)(d & 255);
            const int p = atomicAdd(&cnt[b], 1);
            if (p < 32) {
                stage[b * 32 + ((head[b] + p) & 31)] = val;
            } else {
                const int op = atomicAdd(govf, 1);
                if (op < ovfcap) ovf[op] = ((unsigned long long)b << 32) | val;
            }
        }
        __syncthreads();
        for (int bb = tid; bb < B; bb += 256) {
            int c = cnt[bb]; if (c > 32) c = 32;
            int h = head[bb];
            while (c >= 16) {
                const int gpos = atomicAdd(&gfill[bb], 16);
                if (gpos + 16 <= cap) {
                    unsigned int t[16];
#pragma unroll
                    for (int k = 0; k < 16; ++k) t[k] = stage[bb * 32 + ((h + k) & 31)];
                    uint4* d4 = (uint4*)(ebuf + (size_t)bb * cap + gpos);
                    d4[0] = make_uint4(t[0], t[1], t[2], t[3]);
                    d4[1] = make_uint4(t[4], t[5], t[6], t[7]);
                    d4[2] = make_uint4(t[8], t[9], t[10], t[11]);
                    d4[3] = make_uint4(t[12], t[13], t[14], t[15]);
                }
                h = (h + 16) & 31; c -= 16;
            }
            head[bb] = h; cnt[bb] = c;
        }
        __syncthreads();
    }
    for (int bb = tid; bb < B; bb += 256) {
        int c = cnt[bb]; if (c > 32) c = 32;
        const int h = head[bb];
        if (c > 0) {
            const int gpos = atomicAdd(&gfill[bb], c);
            for (int k = 0; k < c; ++k)
                if (gpos + k < cap) ebuf[(size_t)bb * cap + gpos + k] = stage[bb * 32 + ((h + k) & 31)];
        }
    }
}

__global__ void bin_cleanup(const unsigned long long* __restrict__ ovf,
                            const int* __restrict__ govf, unsigned int* __restrict__ ebuf,
                            int cap, int* __restrict__ gfill, int ovfcap) {
    const int m = min(*govf, ovfcap);
    for (int i = blockIdx.x * 256 + threadIdx.x; i < m; i += gridDim.x * 256) {
        const unsigned long long e = ovf[i];
        const int b = (int)(e >> 32);
        const int pos = atomicAdd(&gfill[b], 1);
        if (pos < cap) ebuf[(size_t)b * cap + pos] = (unsigned int)e;
    }
}

__global__ __launch_bounds__(512) void bucket_base(
    const int* __restrict__ gfill, int* __restrict__ bbase,
    int* __restrict__ row_ptr, int B, int cap, int n) {
    __shared__ int sm[512];
    const int tid = threadIdx.x;
    const int v = (tid < B) ? min(gfill[tid], cap) : 0;
    sm[tid] = v;
    __syncthreads();
    for (int off = 1; off < 512; off <<= 1) {
        int val = (tid >= off) ? sm[tid - off] : 0;
        __syncthreads();
        sm[tid] += val;
        __syncthreads();
    }
    if (tid < B) bbase[tid] = sm[tid] - v;
    if (tid == B - 1) row_ptr[n] = sm[tid];
}

// Per-bucket counting sort -> col_src CSR + row_ptr + dinv.
__global__ __launch_bounds__(512) void bucket_csr(
    const unsigned int* __restrict__ ebuf, int cap, const int* __restrict__ gfill,
    const int* __restrict__ bbase, int* __restrict__ row_ptr,
    float* __restrict__ dinv, int* __restrict__ col_src, int n) {
    __shared__ int hist[256];
    __shared__ int scn[256];
    __shared__ int fill[256];
    const int tid = threadIdx.x;
    const int b = blockIdx.x;
    if (tid < 256) hist[tid] = 0;
    __syncthreads();
    const int m = min(gfill[b], cap);
    const unsigned int* eb = ebuf + (size_t)b * cap;
    for (int i = tid; i < m; i += 512) atomicAdd(&hist[eb[i] & 255u], 1);
    __syncthreads();
    if (tid < 256) scn[tid] = hist[tid];
    __syncthreads();
    for (int off = 1; off < 256; off <<= 1) {
        int val = 0;
        if (tid < 256 && tid >= off) val = scn[tid - off];
        __syncthreads();
        if (tid < 256) scn[tid] += val;
        __syncthreads();
    }
    if (tid < 256) {
        const int excl = scn[tid] - hist[tid];
        fill[tid] = excl;
        const int v = b * 256 + tid;
        if (v < n) {
            row_ptr[v] = bbase[b] + excl;
            dinv[v] = rsqrtf((float)hist[tid] + 1.0f);
        }
    }
    __syncthreads();
    const int base = bbase[b];
    for (int i = tid; i < m; i += 512) {
        const unsigned int e = eb[i];
        const int p = atomicAdd(&fill[e & 255u], 1);
        col_src[base + p] = (int)(e >> 8);
    }
}

// GEMM1: hs1b[v][c] = bf16((sum_k x[v][k]*W1[k][c]) * dinv[v])   (256 -> 64)
__global__ __launch_bounds__(128) void gemm1_kernel(
    const float* __restrict__ x, const float* __restrict__ W1,
    const float* __restrict__ dinv, unsigned short* __restrict__ hs1b, int n) {
    __shared__ float xs[32 * 132];
    __shared__ float wl[128 * 64];
    const int tid = threadIdx.x;
    const int tj = tid & 15;
    const int ti = tid >> 4;
    const int row0 = blockIdx.x * 32;
    float acc[4][4] = {};
    for (int kt = 0; kt < 2; ++kt) {
        const float4* wsrc = (const float4*)(W1 + kt * 128 * 64);
        float4* wdst = (float4*)wl;
#pragma unroll
        for (int i = 0; i < 16; ++i) wdst[tid + 128 * i] = wsrc[tid + 128 * i];
#pragma unroll
        for (int i = 0; i < 8; ++i) {
            const int flat = tid + 128 * i;
            const int r = flat >> 5;
            const int c4 = flat & 31;
            int gr = row0 + r;
            if (gr >= n) gr = n - 1;
            float4 v = *(const float4*)(x + (size_t)gr * 256 + kt * 128 + c4 * 4);
            *(float4*)(xs + r * 132 + c4 * 4) = v;
        }
        __syncthreads();
#pragma unroll 4
        for (int k = 0; k < 128; ++k) {
            const float4 wv = *(const float4*)(wl + k * 64 + tj * 4);
            float xv[4];
#pragma unroll
            for (int j = 0; j < 4; ++j) xv[j] = xs[(ti * 4 + j) * 132 + k];
#pragma unroll
            for (int j = 0; j < 4; ++j) {
                acc[j][0] += xv[j] * wv.x;
                acc[j][1] += xv[j] * wv.y;
                acc[j][2] += xv[j] * wv.z;
                acc[j][3] += xv[j] * wv.w;
            }
        }
        __syncthreads();
    }
#pragma unroll
    for (int j = 0; j < 4; ++j) {
        const int gr = row0 + ti * 4 + j;
        if (gr < n) {
            const float dv = dinv[gr];
            ushort4 o;
            o.x = f2bf(acc[j][0] * dv); o.y = f2bf(acc[j][1] * dv);
            o.z = f2bf(acc[j][2] * dv); o.w = f2bf(acc[j][3] * dv);
            *(ushort4*)(hs1b + (size_t)gr * 64 + tj * 4) = o;
        }
    }
}

// AGG1: wave per node. Lane (g=lane>>4, q=lane&15): each lane loads ushort4
// (8B) -> one wave-load covers 4 full bf16 rows (4 edges). Cross-group
// combine via shfl_xor(16,32). Fused self-term + bias + leaky_relu.
__global__ __launch_bounds__(256) void agg1_kernel(
    const int* __restrict__ row_ptr, const int* __restrict__ col_src,
    const unsigned short* __restrict__ hs1b, const float* __restrict__ dinv,
    const float* __restrict__ b1, float* __restrict__ out1, int n) {
    const int lane = threadIdx.x & 63;
    int v = blockIdx.x * 4 + (threadIdx.x >> 6);
    v = __builtin_amdgcn_readfirstlane(v);
    if (v >= n) return;
    const int g = lane >> 4;
    const int q = lane & 15;
    const int rs = row_ptr[v];
    const int re = row_ptr[v + 1];
    float a0 = 0.f, a1 = 0.f, a2 = 0.f, a3 = 0.f;
    int e = rs;
    // main: 16 edges / step, 4 fat loads in flight
    for (; e + 16 <= re; e += 16) {
        const int cs = col_src[e + q];  // lanes 0-15 hold e..e+15 (dup x4)
        const int s0 = __shfl(cs, 0 + g);
        const int s1 = __shfl(cs, 4 + g);
        const int s2 = __shfl(cs, 8 + g);
        const int s3 = __shfl(cs, 12 + g);
        const ushort4 r0 = *((const ushort4*)(hs1b + (size_t)s0 * 64) + q);
        const ushort4 r1 = *((const ushort4*)(hs1b + (size_t)s1 * 64) + q);
        const ushort4 r2 = *((const ushort4*)(hs1b + (size_t)s2 * 64) + q);
        const ushort4 r3 = *((const ushort4*)(hs1b + (size_t)s3 * 64) + q);
        a0 += bf2f(r0.x) + bf2f(r1.x) + bf2f(r2.x) + bf2f(r3.x);
        a1 += bf2f(r0.y) + bf2f(r1.y) + bf2f(r2.y) + bf2f(r3.y);
        a2 += bf2f(r0.z) + bf2f(r1.z) + bf2f(r2.z) + bf2f(r3.z);
        a3 += bf2f(r0.w) + bf2f(r1.w) + bf2f(r2.w) + bf2f(r3.w);
    }
    // tail: 4 edges / step (group g takes edge e+g)
    for (; e < re; e += 4) {
        if (e + g < re) {
            const int s = col_src[e + g];
            const ushort4 r = *((const ushort4*)(hs1b + (size_t)s * 64) + q);
            a0 += bf2f(r.x); a1 += bf2f(r.y); a2 += bf2f(r.z); a3 += bf2f(r.w);
        }
    }
    // combine the 4 groups: every lane ends with the full column sums
    a0 += __shfl_xor(a0, 16); a1 += __shfl_xor(a1, 16);
    a2 += __shfl_xor(a2, 16); a3 += __shfl_xor(a3, 16);
    a0 += __shfl_xor(a0, 32); a1 += __shfl_xor(a1, 32);
    a2 += __shfl_xor(a2, 32); a3 += __shfl_xor(a3, 32);
    const ushort4 sr = *((const ushort4*)(hs1b + (size_t)v * 64) + q);
    const float dv = dinv[v];
    const float4 bb = *((const float4*)b1 + q);
    float4 res;
    res.x = dv * (a0 + bf2f(sr.x)) + bb.x;
    res.y = dv * (a1 + bf2f(sr.y)) + bb.y;
    res.z = dv * (a2 + bf2f(sr.z)) + bb.z;
    res.w = dv * (a3 + bf2f(sr.w)) + bb.w;
    res.x = res.x > 0.f ? res.x : 0.01f * res.x;
    res.y = res.y > 0.f ? res.y : 0.01f * res.y;
    res.z = res.z > 0.f ? res.z : 0.01f * res.z;
    res.w = res.w > 0.f ? res.w : 0.01f * res.w;
    if (lane < 16) *((float4*)(out1 + (size_t)v * 64) + q) = res;
}

// GEMM2: hs2[v][c] = (sum_k out1[v][k]*W2[k][c]) * dinv[v]   (64 -> 4)
__global__ __launch_bounds__(256) void gemm2_kernel(
    const float* __restrict__ out1, const float* __restrict__ W2,
    const float* __restrict__ dinv, float* __restrict__ hs2, int n) {
    __shared__ float4 wl[64];
    const int tid = threadIdx.x;
    if (tid < 64) wl[tid] = *(const float4*)(W2 + tid * 4);
    __syncthreads();
    const int row = blockIdx.x * 256 + tid;
    if (row >= n) return;
    const float4* xr = (const float4*)(out1 + (size_t)row * 64);
    float ax = 0.f, ay = 0.f, az = 0.f, aw = 0.f;
#pragma unroll
    for (int k4 = 0; k4 < 16; ++k4) {
        const float4 xv = xr[k4];
        const float4 w0 = wl[k4 * 4 + 0], w1 = wl[k4 * 4 + 1];
        const float4 w2 = wl[k4 * 4 + 2], w3 = wl[k4 * 4 + 3];
        ax += xv.x * w0.x + xv.y * w1.x + xv.z * w2.x + xv.w * w3.x;
        ay += xv.x * w0.y + xv.y * w1.y + xv.z * w2.y + xv.w * w3.y;
        az += xv.x * w0.z + xv.y * w1.z + xv.z * w2.z + xv.w * w3.z;
        aw += xv.x * w0.w + xv.y * w1.w + xv.z * w2.w + xv.w * w3.w;
    }
    const float dv = dinv[row];
    float4 o; o.x = ax * dv; o.y = ay * dv; o.z = az * dv; o.w = aw * dv;
    *(float4*)(hs2 + (size_t)row * 4) = o;
}

// AGG2 + softmax: wave per node; lane -> (edge slot = lane>>2, col = lane&3)
__global__ __launch_bounds__(256) void agg2_kernel(
    const int* __restrict__ row_ptr, const int* __restrict__ col_src,
    const float* __restrict__ hs2, const float* __restrict__ dinv,
    const float* __restrict__ b2, float* __restrict__ out, int n) {
    const int lane = threadIdx.x & 63;
    int v = blockIdx.x * 4 + (threadIdx.x >> 6);
    v = __builtin_amdgcn_readfirstlane(v);
    if (v >= n) return;
    const int c = lane & 3;
    const int ei = lane >> 2;
    const int rs = row_ptr[v];
    const int re = row_ptr[v + 1];
    float acc = 0.f;
    for (int e0 = rs; e0 < re; e0 += 16) {
        const int e = e0 + ei;
        if (e < re) {
            const int s = col_src[e];
            acc += hs2[(size_t)s * 4 + c];
        }
    }
    acc += __shfl_xor(acc, 4);
    acc += __shfl_xor(acc, 8);
    acc += __shfl_xor(acc, 16);
    acc += __shfl_xor(acc, 32);
    const float val = dinv[v] * (acc + hs2[(size_t)v * 4 + c]) + b2[c];
    float m = fmaxf(val, __shfl_xor(val, 1));
    m = fmaxf(m, __shfl_xor(m, 2));
    const float ex = __expf(val - m);
    float s = ex + __shfl_xor(ex, 1);
    s += __shfl_xor(s, 2);
    if (lane < 4) out[(size_t)v * 4 + c] = ex / s;
}

extern "C" void kernel_launch(void* const* d_in, const int* in_sizes, int n_in,
                              void* d_out, int out_size, void* d_ws, size_t ws_size,
                              hipStream_t stream) {
    const float* x  = (const float*)d_in[0];
    const void*  ei = d_in[1];
    const float* W1 = (const float*)d_in[2];
    const float* b1 = (const float*)d_in[3];
    const float* W2 = (const float*)d_in[4];
    const float* b2 = (const float*)d_in[5];
    const int n = in_sizes[0] / 256;
    const int E = in_sizes[1] / 2;
    const int B = (n + 255) / 256;

    char* ws = (char*)d_ws;
    size_t off = 0;
    auto alloc = [&](size_t bytes) -> void* {
        void* p = ws + off;
        off += (bytes + 255) & ~(size_t)255;
        return p;
    };
    int*   flag    = (int*)alloc(sizeof(int) * 64);
    int*   gfill   = (int*)alloc(sizeof(int) * (B + 1));  // [B]=govf
    int*   bbase   = (int*)alloc(sizeof(int) * B);
    int*   row_ptr = (int*)alloc(sizeof(int) * (n + 1));
    int*   col_src = (int*)alloc(sizeof(int) * (size_t)E);
    float* dinv    = (float*)alloc(sizeof(float) * n);
    unsigned short* hs1b = (unsigned short*)alloc(sizeof(unsigned short) * (size_t)n * 64);
    float* out1    = (float*)alloc(sizeof(float) * (size_t)n * 64);
    float* hs2     = (float*)alloc(sizeof(float) * (size_t)n * 4);
    int CAP = 16384;
    {
        size_t rem = (ws_size > off) ? (ws_size - off) : 0;
        while (CAP > 9216 && (size_t)B * CAP * 4 + (1u << 20) > rem) CAP -= 1024;
    }
    unsigned int* ebuf = (unsigned int*)alloc(sizeof(unsigned int) * (size_t)B * CAP);
    size_t rem2 = (ws_size > off) ? (ws_size - off) : 0;
    int ovfcap = (int)((rem2 / 8 < (size_t)E) ? rem2 / 8 : (size_t)E);
    unsigned long long* ovf = (unsigned long long*)alloc(sizeof(unsigned long long) * (size_t)ovfcap);
    int* govf = gfill + B;
    (void)n_in; (void)out_size;

    hipMemsetAsync(gfill, 0, sizeof(int) * (B + 1), stream);
    detect_width<<<1, 64, 0, stream>>>((const unsigned int*)ei, flag);
    const size_t smem_bin = (size_t)(B * 32 + 2 * B) * sizeof(unsigned int);
    binstage<<<1024, 256, smem_bin, stream>>>(ei, E, flag, ebuf, CAP, gfill, ovf, govf, ovfcap, B);
    bin_cleanup<<<16, 256, 0, stream>>>(ovf, govf, ebuf, CAP, gfill, ovfcap);
    bucket_base<<<1, 512, 0, stream>>>(gfill, bbase, row_ptr, B, CAP, n);
    bucket_csr<<<B, 512, 0, stream>>>(ebuf, CAP, gfill, bbase, row_ptr, dinv, col_src, n);
    gemm1_kernel<<<(n + 31) / 32, 128, 0, stream>>>(x, W1, dinv, hs1b, n);
    agg1_kernel<<<(n + 3) / 4, 256, 0, stream>>>(row_ptr, col_src, hs1b, dinv, b1, out1, n);
    gemm2_kernel<<<(n + 255) / 256, 256, 0, stream>>>(out1, W2, dinv, hs2, n);
    agg2_kernel<<<(n + 3) / 4, 256, 0, stream>>>(row_ptr, col_src, hs2, dinv, b2, (float*)d_out, n);
}

// Round 5
// 227.999 us; speedup vs baseline: 7.3597x; 1.1575x over previous
//
#include <hip/hip_runtime.h>
#include <hip/hip_bf16.h>
#include <math.h>

// ---------------------------------------------------------------------------
// GCN 2-layer forward. Pipeline:
//   detect width -> binstage (multisplit edges into buckets of 256 dst) ->
//   bucket_base (scan) -> bucket_csr (counting sort -> CSR + dinv) ->
//   gemm1 (MFMA bf16: hs1b = bf16((x@W1) * dinv)) ->
//   agg1 (wave/node, bf16x4 gather) -> gemm2 -> agg2 (+softmax)
// gemm1 rationale (round 4): fp32 VALU version was 82.6us at 12.5% occupancy
// (49.6KB LDS, 128thr). MFMA 16x16x32 bf16: A-frags straight from global x
// (fp32->bf16 in-reg), W1 transposed in LDS (stride 264 = bank-uniform),
// 33.8KB LDS / 256thr -> 4 blocks/CU. bf16 safety proven in round 4 (absmax
// unchanged when hs1 went bf16).
// ---------------------------------------------------------------------------

typedef __attribute__((ext_vector_type(8))) short bf16x8;   // 8 bf16 (4 VGPR)
typedef __attribute__((ext_vector_type(4))) float f32x4;    // MFMA accum

__device__ __forceinline__ int edge_val(const void* ep, size_t idx, int is64) {
    if (is64) return (int)(((const long long*)ep)[idx]);
    return ((const int*)ep)[idx];
}

__device__ __forceinline__ unsigned short f2bf(float f) {  // RNE
    unsigned int u = __float_as_uint(f);
    return (unsigned short)((u + 0x7FFFu + ((u >> 16) & 1u)) >> 16);
}
__device__ __forceinline__ float bf2f(unsigned short b) {
    return __uint_as_float((unsigned int)b << 16);
}

__global__ void detect_width(const unsigned int* __restrict__ ew, int* __restrict__ flag) {
    if (threadIdx.x == 0 && blockIdx.x == 0) {
        int f = 1;
        for (int i = 0; i < 64; ++i)
            if (ew[2 * i + 1] != 0u) { f = 0; break; }
        *flag = f;
    }
}

// Multisplit: LDS ring buffer (32 entries) per bucket, flush 16-entry (64B)
// aligned chunks. Rare overflow -> global fallback list.
__global__ __launch_bounds__(256) void binstage(
    const void* __restrict__ edges, int E, const int* __restrict__ flagp,
    unsigned int* __restrict__ ebuf, int cap, int* __restrict__ gfill,
    unsigned long long* __restrict__ ovf, int* __restrict__ govf, int ovfcap, int B) {
    extern __shared__ unsigned int sm[];
    unsigned int* stage = sm;                  // B * 32
    int* cnt  = (int*)(sm + (size_t)B * 32);   // B
    int* head = cnt + B;                       // B
    const int tid = threadIdx.x;
    for (int i = tid; i < B; i += 256) { cnt[i] = 0; head[i] = 0; }
    __syncthreads();
    const int is64 = *flagp;
    const long long per = ((long long)E + gridDim.x - 1) / gridDim.x;
    const long long s0 = (long long)blockIdx.x * per;
    const long long s1 = (per + s0 < E) ? (s0 + per) : E;
    for (long long base = s0; base < s1; base += 256) {
        const long long i = base + tid;
        if (i < s1) {
            const int d = edge_val(edges, (size_t)E + i, is64);
            const int s = edge_val(edges, (size_t)i, is64);
            const int b = d >> 8;
            const unsigned int val = ((unsigned int)s << 8) | (unsigned int)(d & 255);
            const int p = atomicAdd(&cnt[b], 1);
            if (p < 32) {
                stage[b * 32 + ((head[b] + p) & 31)] = val;
            } else {
                const int op = atomicAdd(govf, 1);
                if (op < ovfcap) ovf[op] = ((unsigned long long)b << 32) | val;
            }
        }
        __syncthreads();
        for (int bb = tid; bb < B; bb += 256) {
            int c = cnt[bb]; if (c > 32) c = 32;
            int h = head[bb];
            while (c >= 16) {
                const int gpos = atomicAdd(&gfill[bb], 16);
                if (gpos + 16 <= cap) {
                    unsigned int t[16];
#pragma unroll
                    for (int k = 0; k < 16; ++k) t[k] = stage[bb * 32 + ((h + k) & 31)];
                    uint4* d4 = (uint4*)(ebuf + (size_t)bb * cap + gpos);
                    d4[0] = make_uint4(t[0], t[1], t[2], t[3]);
                    d4[1] = make_uint4(t[4], t[5], t[6], t[7]);
                    d4[2] = make_uint4(t[8], t[9], t[10], t[11]);
                    d4[3] = make_uint4(t[12], t[13], t[14], t[15]);
                }
                h = (h + 16) & 31; c -= 16;
            }
            head[bb] = h; cnt[bb] = c;
        }
        __syncthreads();
    }
    for (int bb = tid; bb < B; bb += 256) {
        int c = cnt[bb]; if (c > 32) c = 32;
        const int h = head[bb];
        if (c > 0) {
            const int gpos = atomicAdd(&gfill[bb], c);
            for (int k = 0; k < c; ++k)
                if (gpos + k < cap) ebuf[(size_t)bb * cap + gpos + k] = stage[bb * 32 + ((h + k) & 31)];
        }
    }
}

__global__ void bin_cleanup(const unsigned long long* __restrict__ ovf,
                            const int* __restrict__ govf, unsigned int* __restrict__ ebuf,
                            int cap, int* __restrict__ gfill, int ovfcap) {
    const int m = min(*govf, ovfcap);
    for (int i = blockIdx.x * 256 + threadIdx.x; i < m; i += gridDim.x * 256) {
        const unsigned long long e = ovf[i];
        const int b = (int)(e >> 32);
        const int pos = atomicAdd(&gfill[b], 1);
        if (pos < cap) ebuf[(size_t)b * cap + pos] = (unsigned int)e;
    }
}

__global__ __launch_bounds__(512) void bucket_base(
    const int* __restrict__ gfill, int* __restrict__ bbase,
    int* __restrict__ row_ptr, int B, int cap, int n) {
    __shared__ int sm[512];
    const int tid = threadIdx.x;
    const int v = (tid < B) ? min(gfill[tid], cap) : 0;
    sm[tid] = v;
    __syncthreads();
    for (int off = 1; off < 512; off <<= 1) {
        int val = (tid >= off) ? sm[tid - off] : 0;
        __syncthreads();
        sm[tid] += val;
        __syncthreads();
    }
    if (tid < B) bbase[tid] = sm[tid] - v;
    if (tid == B - 1) row_ptr[n] = sm[tid];
}

// Per-bucket counting sort -> col_src CSR + row_ptr + dinv.
__global__ __launch_bounds__(512) void bucket_csr(
    const unsigned int* __restrict__ ebuf, int cap, const int* __restrict__ gfill,
    const int* __restrict__ bbase, int* __restrict__ row_ptr,
    float* __restrict__ dinv, int* __restrict__ col_src, int n) {
    __shared__ int hist[256];
    __shared__ int scn[256];
    __shared__ int fill[256];
    const int tid = threadIdx.x;
    const int b = blockIdx.x;
    if (tid < 256) hist[tid] = 0;
    __syncthreads();
    const int m = min(gfill[b], cap);
    const unsigned int* eb = ebuf + (size_t)b * cap;
    for (int i = tid; i < m; i += 512) atomicAdd(&hist[eb[i] & 255u], 1);
    __syncthreads();
    if (tid < 256) scn[tid] = hist[tid];
    __syncthreads();
    for (int off = 1; off < 256; off <<= 1) {
        int val = 0;
        if (tid < 256 && tid >= off) val = scn[tid - off];
        __syncthreads();
        if (tid < 256) scn[tid] += val;
        __syncthreads();
    }
    if (tid < 256) {
        const int excl = scn[tid] - hist[tid];
        fill[tid] = excl;
        const int v = b * 256 + tid;
        if (v < n) {
            row_ptr[v] = bbase[b] + excl;
            dinv[v] = rsqrtf((float)hist[tid] + 1.0f);
        }
    }
    __syncthreads();
    const int base = bbase[b];
    for (int i = tid; i < m; i += 512) {
        const unsigned int e = eb[i];
        const int p = atomicAdd(&fill[e & 255u], 1);
        col_src[base + p] = (int)(e >> 8);
    }
}

// GEMM1 (MFMA): hs1b[v][c] = bf16((x@W1)[v][c] * dinv[v]),  256 -> 64.
// Block: 256 thr = 4 waves, 64 rows. Wave: 16 rows x 64 cols = 4 col-tiles x
// 8 k-steps of v_mfma_f32_16x16x32_bf16. A-frags from global (fp32->bf16),
// B from LDS-transposed W1 (stride 264 bf16 -> uniform 8-access/bank).
__global__ __launch_bounds__(256) void gemm1_kernel(
    const float* __restrict__ x, const float* __restrict__ W1,
    const float* __restrict__ dinv, unsigned short* __restrict__ hs1b, int n) {
    __shared__ unsigned short wt[64 * 264];  // [col][k], 33792 B
    const int tid = threadIdx.x;
    // stage W1 (256x64 fp32) -> wt[c][k] bf16
    for (int i = tid; i < 4096; i += 256) {
        const int k = i >> 4;
        const int c0 = (i & 15) * 4;
        const float4 w = *((const float4*)W1 + i);
        wt[(c0 + 0) * 264 + k] = f2bf(w.x);
        wt[(c0 + 1) * 264 + k] = f2bf(w.y);
        wt[(c0 + 2) * 264 + k] = f2bf(w.z);
        wt[(c0 + 3) * 264 + k] = f2bf(w.w);
    }
    __syncthreads();

    const int lane = tid & 63;
    const int wid = tid >> 6;
    const int row0 = blockIdx.x * 64 + wid * 16;
    const int rr = lane & 15;
    const int kh = lane >> 4;  // 0..3

    union FragU { bf16x8 v; unsigned short u[8]; };
    // A-frags: row = row0+rr, k = ks*32 + kh*8 + [0..7]
    bf16x8 af[8];
    {
        int r = row0 + rr;
        if (r >= n) r = n - 1;
        const float* xr = x + (size_t)r * 256 + kh * 8;
#pragma unroll
        for (int ks = 0; ks < 8; ++ks) {
            const float4 p0 = *(const float4*)(xr + ks * 32);
            const float4 p1 = *(const float4*)(xr + ks * 32 + 4);
            FragU f;
            f.u[0] = f2bf(p0.x); f.u[1] = f2bf(p0.y);
            f.u[2] = f2bf(p0.z); f.u[3] = f2bf(p0.w);
            f.u[4] = f2bf(p1.x); f.u[5] = f2bf(p1.y);
            f.u[6] = f2bf(p1.z); f.u[7] = f2bf(p1.w);
            af[ks] = f.v;
        }
    }
    f32x4 acc[4];
#pragma unroll
    for (int ct = 0; ct < 4; ++ct) acc[ct] = (f32x4){0.f, 0.f, 0.f, 0.f};

#pragma unroll
    for (int ct = 0; ct < 4; ++ct) {
        const unsigned short* wcol = wt + (ct * 16 + rr) * 264 + kh * 8;
#pragma unroll
        for (int ks = 0; ks < 8; ++ks) {
            const bf16x8 bf = *(const bf16x8*)(wcol + ks * 32);
            acc[ct] = __builtin_amdgcn_mfma_f32_16x16x32_bf16(af[ks], bf, acc[ct], 0, 0, 0);
        }
    }
    // D: col = lane&15 (within tile), row = kh*4 + j
#pragma unroll
    for (int j = 0; j < 4; ++j) {
        const int gr = row0 + kh * 4 + j;
        if (gr < n) {
            const float dv = dinv[gr];
#pragma unroll
            for (int ct = 0; ct < 4; ++ct)
                hs1b[(size_t)gr * 64 + ct * 16 + rr] = f2bf(acc[ct][j] * dv);
        }
    }
}

// AGG1: wave per node. Lane (g=lane>>4, q=lane&15): each lane loads ushort4
// (8B) -> one wave-load covers 4 full bf16 rows (4 edges). Cross-group
// combine via shfl_xor(16,32). Fused self-term + bias + leaky_relu.
__global__ __launch_bounds__(256) void agg1_kernel(
    const int* __restrict__ row_ptr, const int* __restrict__ col_src,
    const unsigned short* __restrict__ hs1b, const float* __restrict__ dinv,
    const float* __restrict__ b1, float* __restrict__ out1, int n) {
    const int lane = threadIdx.x & 63;
    int v = blockIdx.x * 4 + (threadIdx.x >> 6);
    v = __builtin_amdgcn_readfirstlane(v);
    if (v >= n) return;
    const int g = lane >> 4;
    const int q = lane & 15;
    const int rs = row_ptr[v];
    const int re = row_ptr[v + 1];
    float a0 = 0.f, a1 = 0.f, a2 = 0.f, a3 = 0.f;
    int e = rs;
    for (; e + 16 <= re; e += 16) {
        const int cs = col_src[e + q];
        const int s0 = __shfl(cs, 0 + g);
        const int s1 = __shfl(cs, 4 + g);
        const int s2 = __shfl(cs, 8 + g);
        const int s3 = __shfl(cs, 12 + g);
        const ushort4 r0 = *((const ushort4*)(hs1b + (size_t)s0 * 64) + q);
        const ushort4 r1 = *((const ushort4*)(hs1b + (size_t)s1 * 64) + q);
        const ushort4 r2 = *((const ushort4*)(hs1b + (size_t)s2 * 64) + q);
        const ushort4 r3 = *((const ushort4*)(hs1b + (size_t)s3 * 64) + q);
        a0 += bf2f(r0.x) + bf2f(r1.x) + bf2f(r2.x) + bf2f(r3.x);
        a1 += bf2f(r0.y) + bf2f(r1.y) + bf2f(r2.y) + bf2f(r3.y);
        a2 += bf2f(r0.z) + bf2f(r1.z) + bf2f(r2.z) + bf2f(r3.z);
        a3 += bf2f(r0.w) + bf2f(r1.w) + bf2f(r2.w) + bf2f(r3.w);
    }
    for (; e < re; e += 4) {
        if (e + g < re) {
            const int s = col_src[e + g];
            const ushort4 r = *((const ushort4*)(hs1b + (size_t)s * 64) + q);
            a0 += bf2f(r.x); a1 += bf2f(r.y); a2 += bf2f(r.z); a3 += bf2f(r.w);
        }
    }
    a0 += __shfl_xor(a0, 16); a1 += __shfl_xor(a1, 16);
    a2 += __shfl_xor(a2, 16); a3 += __shfl_xor(a3, 16);
    a0 += __shfl_xor(a0, 32); a1 += __shfl_xor(a1, 32);
    a2 += __shfl_xor(a2, 32); a3 += __shfl_xor(a3, 32);
    const ushort4 sr = *((const ushort4*)(hs1b + (size_t)v * 64) + q);
    const float dv = dinv[v];
    const float4 bb = *((const float4*)b1 + q);
    float4 res;
    res.x = dv * (a0 + bf2f(sr.x)) + bb.x;
    res.y = dv * (a1 + bf2f(sr.y)) + bb.y;
    res.z = dv * (a2 + bf2f(sr.z)) + bb.z;
    res.w = dv * (a3 + bf2f(sr.w)) + bb.w;
    res.x = res.x > 0.f ? res.x : 0.01f * res.x;
    res.y = res.y > 0.f ? res.y : 0.01f * res.y;
    res.z = res.z > 0.f ? res.z : 0.01f * res.z;
    res.w = res.w > 0.f ? res.w : 0.01f * res.w;
    if (lane < 16) *((float4*)(out1 + (size_t)v * 64) + q) = res;
}

// GEMM2: hs2[v][c] = (sum_k out1[v][k]*W2[k][c]) * dinv[v]   (64 -> 4)
__global__ __launch_bounds__(256) void gemm2_kernel(
    const float* __restrict__ out1, const float* __restrict__ W2,
    const float* __restrict__ dinv, float* __restrict__ hs2, int n) {
    __shared__ float4 wl[64];
    const int tid = threadIdx.x;
    if (tid < 64) wl[tid] = *(const float4*)(W2 + tid * 4);
    __syncthreads();
    const int row = blockIdx.x * 256 + tid;
    if (row >= n) return;
    const float4* xr = (const float4*)(out1 + (size_t)row * 64);
    float ax = 0.f, ay = 0.f, az = 0.f, aw = 0.f;
#pragma unroll
    for (int k4 = 0; k4 < 16; ++k4) {
        const float4 xv = xr[k4];
        const float4 w0 = wl[k4 * 4 + 0], w1 = wl[k4 * 4 + 1];
        const float4 w2 = wl[k4 * 4 + 2], w3 = wl[k4 * 4 + 3];
        ax += xv.x * w0.x + xv.y * w1.x + xv.z * w2.x + xv.w * w3.x;
        ay += xv.x * w0.y + xv.y * w1.y + xv.z * w2.y + xv.w * w3.y;
        az += xv.x * w0.z + xv.y * w1.z + xv.z * w2.z + xv.w * w3.z;
        aw += xv.x * w0.w + xv.y * w1.w + xv.z * w2.w + xv.w * w3.w;
    }
    const float dv = dinv[row];
    float4 o; o.x = ax * dv; o.y = ay * dv; o.z = az * dv; o.w = aw * dv;
    *(float4*)(hs2 + (size_t)row * 4) = o;
}

// AGG2 + softmax: wave per node; lane -> (edge slot = lane>>2, col = lane&3)
__global__ __launch_bounds__(256) void agg2_kernel(
    const int* __restrict__ row_ptr, const int* __restrict__ col_src,
    const float* __restrict__ hs2, const float* __restrict__ dinv,
    const float* __restrict__ b2, float* __restrict__ out, int n) {
    const int lane = threadIdx.x & 63;
    int v = blockIdx.x * 4 + (threadIdx.x >> 6);
    v = __builtin_amdgcn_readfirstlane(v);
    if (v >= n) return;
    const int c = lane & 3;
    const int ei = lane >> 2;
    const int rs = row_ptr[v];
    const int re = row_ptr[v + 1];
    float acc = 0.f;
    for (int e0 = rs; e0 < re; e0 += 16) {
        const int e = e0 + ei;
        if (e < re) {
            const int s = col_src[e];
            acc += hs2[(size_t)s * 4 + c];
        }
    }
    acc += __shfl_xor(acc, 4);
    acc += __shfl_xor(acc, 8);
    acc += __shfl_xor(acc, 16);
    acc += __shfl_xor(acc, 32);
    const float val = dinv[v] * (acc + hs2[(size_t)v * 4 + c]) + b2[c];
    float m = fmaxf(val, __shfl_xor(val, 1));
    m = fmaxf(m, __shfl_xor(m, 2));
    const float ex = __expf(val - m);
    float s = ex + __shfl_xor(ex, 1);
    s += __shfl_xor(s, 2);
    if (lane < 4) out[(size_t)v * 4 + c] = ex / s;
}

extern "C" void kernel_launch(void* const* d_in, const int* in_sizes, int n_in,
                              void* d_out, int out_size, void* d_ws, size_t ws_size,
                              hipStream_t stream) {
    const float* x  = (const float*)d_in[0];
    const void*  ei = d_in[1];
    const float* W1 = (const float*)d_in[2];
    const float* b1 = (const float*)d_in[3];
    const float* W2 = (const float*)d_in[4];
    const float* b2 = (const float*)d_in[5];
    const int n = in_sizes[0] / 256;
    const int E = in_sizes[1] / 2;
    const int B = (n + 255) / 256;

    char* ws = (char*)d_ws;
    size_t off = 0;
    auto alloc = [&](size_t bytes) -> void* {
        void* p = ws + off;
        off += (bytes + 255) & ~(size_t)255;
        return p;
    };
    int*   flag    = (int*)alloc(sizeof(int) * 64);
    int*   gfill   = (int*)alloc(sizeof(int) * (B + 1));  // [B]=govf
    int*   bbase   = (int*)alloc(sizeof(int) * B);
    int*   row_ptr = (int*)alloc(sizeof(int) * (n + 1));
    int*   col_src = (int*)alloc(sizeof(int) * (size_t)E);
    float* dinv    = (float*)alloc(sizeof(float) * n);
    unsigned short* hs1b = (unsigned short*)alloc(sizeof(unsigned short) * (size_t)n * 64);
    float* out1    = (float*)alloc(sizeof(float) * (size_t)n * 64);
    float* hs2     = (float*)alloc(sizeof(float) * (size_t)n * 4);
    int CAP = 16384;
    {
        size_t rem = (ws_size > off) ? (ws_size - off) : 0;
        while (CAP > 9216 && (size_t)B * CAP * 4 + (1u << 20) > rem) CAP -= 1024;
    }
    unsigned int* ebuf = (unsigned int*)alloc(sizeof(unsigned int) * (size_t)B * CAP);
    size_t rem2 = (ws_size > off) ? (ws_size - off) : 0;
    int ovfcap = (int)((rem2 / 8 < (size_t)E) ? rem2 / 8 : (size_t)E);
    unsigned long long* ovf = (unsigned long long*)alloc(sizeof(unsigned long long) * (size_t)ovfcap);
    int* govf = gfill + B;
    (void)n_in; (void)out_size;

    hipMemsetAsync(gfill, 0, sizeof(int) * (B + 1), stream);
    detect_width<<<1, 64, 0, stream>>>((const unsigned int*)ei, flag);
    const size_t smem_bin = (size_t)(B * 32 + 2 * B) * sizeof(unsigned int);
    binstage<<<1024, 256, smem_bin, stream>>>(ei, E, flag, ebuf, CAP, gfill, ovf, govf, ovfcap, B);
    bin_cleanup<<<16, 256, 0, stream>>>(ovf, govf, ebuf, CAP, gfill, ovfcap);
    bucket_base<<<1, 512, 0, stream>>>(gfill, bbase, row_ptr, B, CAP, n);
    bucket_csr<<<B, 512, 0, stream>>>(ebuf, CAP, gfill, bbase, row_ptr, dinv, col_src, n);
    gemm1_kernel<<<(n + 63) / 64, 256, 0, stream>>>(x, W1, dinv, hs1b, n);
    agg1_kernel<<<(n + 3) / 4, 256, 0, stream>>>(row_ptr, col_src, hs1b, dinv, b1, out1, n);
    gemm2_kernel<<<(n + 255) / 256, 256, 0, stream>>>(out1, W2, dinv, hs2, n);
    agg2_kernel<<<(n + 3) / 4, 256, 0, stream>>>(row_ptr, col_src, hs2, dinv, b2, (float*)d_out, n);
}

// Round 6
// 211.165 us; speedup vs baseline: 7.9464x; 1.0797x over previous
//
#include <hip/hip_runtime.h>
#include <hip/hip_bf16.h>
#include <math.h>

// ---------------------------------------------------------------------------
// GCN 2-layer forward. Pipeline (round 6):
//   detect width -> hist_pass (per-block bucket histogram) -> col_scan
//   (exclusive scan over blocks per bucket) -> base_scan (bucket bases) ->
//   scatter_pass (exact-position multisplit, no global atomics) ->
//   bucket_csr (per-bucket counting sort -> CSR + dinv) ->
//   gemm1 (MFMA bf16) -> agg1 (wave/node bf16 gather + FUSED gemm2 epilogue)
//   -> agg2 (+softmax)
// Round-5 evidence: agg1 65us (structural gather), gemm1 <30us; remaining
// ~130us was the atomic-ring multisplit + out1 round trip + launches.
// ---------------------------------------------------------------------------

#define NB 512    // multisplit blocks (hist & scatter must match)
#define MAXB 512  // max buckets (n <= 131072)

typedef __attribute__((ext_vector_type(8))) short bf16x8;
typedef __attribute__((ext_vector_type(4))) float f32x4;

__device__ __forceinline__ int edge_val(const void* ep, size_t idx, int is64) {
    if (is64) return (int)(((const long long*)ep)[idx]);
    return ((const int*)ep)[idx];
}

__device__ __forceinline__ unsigned short f2bf(float f) {  // RNE
    unsigned int u = __float_as_uint(f);
    return (unsigned short)((u + 0x7FFFu + ((u >> 16) & 1u)) >> 16);
}
__device__ __forceinline__ float bf2f(unsigned short b) {
    return __uint_as_float((unsigned int)b << 16);
}

__global__ void detect_width(const unsigned int* __restrict__ ew, int* __restrict__ flag) {
    if (threadIdx.x == 0 && blockIdx.x == 0) {
        int f = 1;
        for (int i = 0; i < 64; ++i)
            if (ew[2 * i + 1] != 0u) { f = 0; break; }
        *flag = f;
    }
}

// Pass A: per-block histogram of dst buckets (reads dst half only).
__global__ __launch_bounds__(256) void hist_pass(
    const void* __restrict__ edges, int E, const int* __restrict__ flagp,
    int* __restrict__ ghist, int B) {
    __shared__ int hist[MAXB];
    const int tid = threadIdx.x;
    for (int i = tid; i < B; i += 256) hist[i] = 0;
    __syncthreads();
    const int is64 = *flagp;
    const int per = (E + NB - 1) / NB;
    const int s0 = blockIdx.x * per;
    const int s1 = min(s0 + per, E);
    for (int i = s0 + tid; i < s1; i += 256) {
        const int d = edge_val(edges, (size_t)E + i, is64);
        atomicAdd(&hist[d >> 8], 1);
    }
    __syncthreads();
    for (int i = tid; i < B; i += 256) ghist[(size_t)blockIdx.x * B + i] = hist[i];
}

// Column scan: for bucket b, exclusive scan of ghist[blk][b] over blk.
__global__ __launch_bounds__(NB) void col_scan(
    const int* __restrict__ ghist, int* __restrict__ goff,
    int* __restrict__ bsum, int B) {
    __shared__ int sm[NB];
    const int tid = threadIdx.x;
    const int b = blockIdx.x;
    const int v = ghist[(size_t)tid * B + b];
    sm[tid] = v;
    __syncthreads();
    for (int off = 1; off < NB; off <<= 1) {
        int val = (tid >= off) ? sm[tid - off] : 0;
        __syncthreads();
        sm[tid] += val;
        __syncthreads();
    }
    goff[(size_t)tid * B + b] = sm[tid] - v;
    if (tid == NB - 1) bsum[b] = sm[tid];
}

// Bucket-base exclusive scan; bbase[B] = E; row_ptr[n] = E.
__global__ __launch_bounds__(512) void base_scan(
    const int* __restrict__ bsum, int* __restrict__ bbase,
    int* __restrict__ row_ptr, int B, int n, int E) {
    __shared__ int sm[512];
    const int tid = threadIdx.x;
    const int v = (tid < B) ? bsum[tid] : 0;
    sm[tid] = v;
    __syncthreads();
    for (int off = 1; off < 512; off <<= 1) {
        int val = (tid >= off) ? sm[tid - off] : 0;
        __syncthreads();
        sm[tid] += val;
        __syncthreads();
    }
    if (tid < B) bbase[tid] = sm[tid] - v;
    if (tid == 0) { bbase[B] = E; row_ptr[n] = E; }
}

// Pass B: scatter each edge to its exact position (LDS offsets only).
__global__ __launch_bounds__(256) void scatter_pass(
    const void* __restrict__ edges, int E, const int* __restrict__ flagp,
    const int* __restrict__ goff, const int* __restrict__ bbase,
    unsigned int* __restrict__ ebuf, int B) {
    __shared__ int off[MAXB];
    const int tid = threadIdx.x;
    for (int i = tid; i < B; i += 256) off[i] = bbase[i] + goff[(size_t)blockIdx.x * B + i];
    __syncthreads();
    const int is64 = *flagp;
    const int per = (E + NB - 1) / NB;
    const int s0 = blockIdx.x * per;
    const int s1 = min(s0 + per, E);
    for (int i = s0 + tid; i < s1; i += 256) {
        const int d = edge_val(edges, (size_t)E + i, is64);
        const int s = edge_val(edges, (size_t)i, is64);
        const int pos = atomicAdd(&off[d >> 8], 1);
        ebuf[pos] = ((unsigned int)s << 8) | (unsigned int)(d & 255);
    }
}

// Per-bucket counting sort -> col_src CSR + row_ptr + dinv.
__global__ __launch_bounds__(512) void bucket_csr(
    const unsigned int* __restrict__ ebuf, const int* __restrict__ bbase,
    int* __restrict__ row_ptr, float* __restrict__ dinv,
    int* __restrict__ col_src, int n) {
    __shared__ int hist[256];
    __shared__ int scn[256];
    __shared__ int fill[256];
    const int tid = threadIdx.x;
    const int b = blockIdx.x;
    if (tid < 256) hist[tid] = 0;
    __syncthreads();
    const int base = bbase[b];
    const int m = bbase[b + 1] - base;
    const unsigned int* eb = ebuf + base;
    for (int i = tid; i < m; i += 512) atomicAdd(&hist[eb[i] & 255u], 1);
    __syncthreads();
    if (tid < 256) scn[tid] = hist[tid];
    __syncthreads();
    for (int off = 1; off < 256; off <<= 1) {
        int val = 0;
        if (tid < 256 && tid >= off) val = scn[tid - off];
        __syncthreads();
        if (tid < 256) scn[tid] += val;
        __syncthreads();
    }
    if (tid < 256) {
        const int excl = scn[tid] - hist[tid];
        fill[tid] = excl;
        const int v = b * 256 + tid;
        if (v < n) {
            row_ptr[v] = base + excl;
            dinv[v] = rsqrtf((float)hist[tid] + 1.0f);
        }
    }
    __syncthreads();
    for (int i = tid; i < m; i += 512) {
        const unsigned int e = eb[i];
        const int p = atomicAdd(&fill[e & 255u], 1);
        col_src[base + p] = (int)(e >> 8);
    }
}

// GEMM1 (MFMA): hs1b[v][c] = bf16((x@W1)[v][c] * dinv[v]),  256 -> 64.
__global__ __launch_bounds__(256) void gemm1_kernel(
    const float* __restrict__ x, const float* __restrict__ W1,
    const float* __restrict__ dinv, unsigned short* __restrict__ hs1b, int n) {
    __shared__ unsigned short wt[64 * 264];  // [col][k], 33792 B
    const int tid = threadIdx.x;
    for (int i = tid; i < 4096; i += 256) {
        const int k = i >> 4;
        const int c0 = (i & 15) * 4;
        const float4 w = *((const float4*)W1 + i);
        wt[(c0 + 0) * 264 + k] = f2bf(w.x);
        wt[(c0 + 1) * 264 + k] = f2bf(w.y);
        wt[(c0 + 2) * 264 + k] = f2bf(w.z);
        wt[(c0 + 3) * 264 + k] = f2bf(w.w);
    }
    __syncthreads();

    const int lane = tid & 63;
    const int wid = tid >> 6;
    const int row0 = blockIdx.x * 64 + wid * 16;
    const int rr = lane & 15;
    const int kh = lane >> 4;

    union FragU { bf16x8 v; unsigned short u[8]; };
    bf16x8 af[8];
    {
        int r = row0 + rr;
        if (r >= n) r = n - 1;
        const float* xr = x + (size_t)r * 256 + kh * 8;
#pragma unroll
        for (int ks = 0; ks < 8; ++ks) {
            const float4 p0 = *(const float4*)(xr + ks * 32);
            const float4 p1 = *(const float4*)(xr + ks * 32 + 4);
            FragU f;
            f.u[0] = f2bf(p0.x); f.u[1] = f2bf(p0.y);
            f.u[2] = f2bf(p0.z); f.u[3] = f2bf(p0.w);
            f.u[4] = f2bf(p1.x); f.u[5] = f2bf(p1.y);
            f.u[6] = f2bf(p1.z); f.u[7] = f2bf(p1.w);
            af[ks] = f.v;
        }
    }
    f32x4 acc[4];
#pragma unroll
    for (int ct = 0; ct < 4; ++ct) acc[ct] = (f32x4){0.f, 0.f, 0.f, 0.f};
#pragma unroll
    for (int ct = 0; ct < 4; ++ct) {
        const unsigned short* wcol = wt + (ct * 16 + rr) * 264 + kh * 8;
#pragma unroll
        for (int ks = 0; ks < 8; ++ks) {
            const bf16x8 bf = *(const bf16x8*)(wcol + ks * 32);
            acc[ct] = __builtin_amdgcn_mfma_f32_16x16x32_bf16(af[ks], bf, acc[ct], 0, 0, 0);
        }
    }
#pragma unroll
    for (int j = 0; j < 4; ++j) {
        const int gr = row0 + kh * 4 + j;
        if (gr < n) {
            const float dv = dinv[gr];
#pragma unroll
            for (int ct = 0; ct < 4; ++ct)
                hs1b[(size_t)gr * 64 + ct * 16 + rr] = f2bf(acc[ct][j] * dv);
        }
    }
}

// AGG1 + fused GEMM2: wave per node. Gather bf16 rows (4 rows per wave-load),
// leaky(dinv*(sum+self)+b1) -> in-wave res@W2 (16-lane shfl reduce) ->
// hs2[v] = (out1@W2)*dinv. out1 never materialized.
__global__ __launch_bounds__(256) void agg1_kernel(
    const int* __restrict__ row_ptr, const int* __restrict__ col_src,
    const unsigned short* __restrict__ hs1b, const float* __restrict__ dinv,
    const float* __restrict__ b1, const float* __restrict__ W2,
    float* __restrict__ hs2, int n) {
    const int lane = threadIdx.x & 63;
    int v = blockIdx.x * 4 + (threadIdx.x >> 6);
    v = __builtin_amdgcn_readfirstlane(v);
    if (v >= n) return;
    const int g = lane >> 4;
    const int q = lane & 15;
    const int rs = row_ptr[v];
    const int re = row_ptr[v + 1];
    float a0 = 0.f, a1 = 0.f, a2 = 0.f, a3 = 0.f;
    int e = rs;
    for (; e + 16 <= re; e += 16) {
        const int cs = col_src[e + q];
        const int s0 = __shfl(cs, 0 + g);
        const int s1 = __shfl(cs, 4 + g);
        const int s2 = __shfl(cs, 8 + g);
        const int s3 = __shfl(cs, 12 + g);
        const ushort4 r0 = *((const ushort4*)(hs1b + (size_t)s0 * 64) + q);
        const ushort4 r1 = *((const ushort4*)(hs1b + (size_t)s1 * 64) + q);
        const ushort4 r2 = *((const ushort4*)(hs1b + (size_t)s2 * 64) + q);
        const ushort4 r3 = *((const ushort4*)(hs1b + (size_t)s3 * 64) + q);
        a0 += bf2f(r0.x) + bf2f(r1.x) + bf2f(r2.x) + bf2f(r3.x);
        a1 += bf2f(r0.y) + bf2f(r1.y) + bf2f(r2.y) + bf2f(r3.y);
        a2 += bf2f(r0.z) + bf2f(r1.z) + bf2f(r2.z) + bf2f(r3.z);
        a3 += bf2f(r0.w) + bf2f(r1.w) + bf2f(r2.w) + bf2f(r3.w);
    }
    for (; e < re; e += 4) {
        if (e + g < re) {
            const int s = col_src[e + g];
            const ushort4 r = *((const ushort4*)(hs1b + (size_t)s * 64) + q);
            a0 += bf2f(r.x); a1 += bf2f(r.y); a2 += bf2f(r.z); a3 += bf2f(r.w);
        }
    }
    a0 += __shfl_xor(a0, 16); a1 += __shfl_xor(a1, 16);
    a2 += __shfl_xor(a2, 16); a3 += __shfl_xor(a3, 16);
    a0 += __shfl_xor(a0, 32); a1 += __shfl_xor(a1, 32);
    a2 += __shfl_xor(a2, 32); a3 += __shfl_xor(a3, 32);
    const ushort4 sr = *((const ushort4*)(hs1b + (size_t)v * 64) + q);
    const float dv = dinv[v];
    const float4 bb = *((const float4*)b1 + q);
    float4 res;
    res.x = dv * (a0 + bf2f(sr.x)) + bb.x;
    res.y = dv * (a1 + bf2f(sr.y)) + bb.y;
    res.z = dv * (a2 + bf2f(sr.z)) + bb.z;
    res.w = dv * (a3 + bf2f(sr.w)) + bb.w;
    res.x = res.x > 0.f ? res.x : 0.01f * res.x;
    res.y = res.y > 0.f ? res.y : 0.01f * res.y;
    res.z = res.z > 0.f ? res.z : 0.01f * res.z;
    res.w = res.w > 0.f ? res.w : 0.01f * res.w;
    // fused gemm2: p = res . W2[4q..4q+3][:]; reduce over q (16 lanes)
    const float4* W2v = (const float4*)W2;
    const float4 w0 = W2v[q * 4 + 0], w1 = W2v[q * 4 + 1];
    const float4 w2 = W2v[q * 4 + 2], w3 = W2v[q * 4 + 3];
    float4 p;
    p.x = res.x * w0.x + res.y * w1.x + res.z * w2.x + res.w * w3.x;
    p.y = res.x * w0.y + res.y * w1.y + res.z * w2.y + res.w * w3.y;
    p.z = res.x * w0.z + res.y * w1.z + res.z * w2.z + res.w * w3.z;
    p.w = res.x * w0.w + res.y * w1.w + res.z * w2.w + res.w * w3.w;
#pragma unroll
    for (int s = 1; s < 16; s <<= 1) {
        p.x += __shfl_xor(p.x, s); p.y += __shfl_xor(p.y, s);
        p.z += __shfl_xor(p.z, s); p.w += __shfl_xor(p.w, s);
    }
    if (lane == 0) {
        float4 o; o.x = p.x * dv; o.y = p.y * dv; o.z = p.z * dv; o.w = p.w * dv;
        *(float4*)(hs2 + (size_t)v * 4) = o;
    }
}

// AGG2 + softmax: wave per node; lane -> (edge slot = lane>>2, col = lane&3)
__global__ __launch_bounds__(256) void agg2_kernel(
    const int* __restrict__ row_ptr, const int* __restrict__ col_src,
    const float* __restrict__ hs2, const float* __restrict__ dinv,
    const float* __restrict__ b2, float* __restrict__ out, int n) {
    const int lane = threadIdx.x & 63;
    int v = blockIdx.x * 4 + (threadIdx.x >> 6);
    v = __builtin_amdgcn_readfirstlane(v);
    if (v >= n) return;
    const int c = lane & 3;
    const int ei = lane >> 2;
    const int rs = row_ptr[v];
    const int re = row_ptr[v + 1];
    float acc = 0.f;
    for (int e0 = rs; e0 < re; e0 += 16) {
        const int e = e0 + ei;
        if (e < re) {
            const int s = col_src[e];
            acc += hs2[(size_t)s * 4 + c];
        }
    }
    acc += __shfl_xor(acc, 4);
    acc += __shfl_xor(acc, 8);
    acc += __shfl_xor(acc, 16);
    acc += __shfl_xor(acc, 32);
    const float val = dinv[v] * (acc + hs2[(size_t)v * 4 + c]) + b2[c];
    float m = fmaxf(val, __shfl_xor(val, 1));
    m = fmaxf(m, __shfl_xor(m, 2));
    const float ex = __expf(val - m);
    float s = ex + __shfl_xor(ex, 1);
    s += __shfl_xor(s, 2);
    if (lane < 4) out[(size_t)v * 4 + c] = ex / s;
}

extern "C" void kernel_launch(void* const* d_in, const int* in_sizes, int n_in,
                              void* d_out, int out_size, void* d_ws, size_t ws_size,
                              hipStream_t stream) {
    const float* x  = (const float*)d_in[0];
    const void*  ei = d_in[1];
    const float* W1 = (const float*)d_in[2];
    const float* b1 = (const float*)d_in[3];
    const float* W2 = (const float*)d_in[4];
    const float* b2 = (const float*)d_in[5];
    const int n = in_sizes[0] / 256;
    const int E = in_sizes[1] / 2;
    const int B = (n + 255) / 256;  // <= MAXB for n <= 131072

    char* ws = (char*)d_ws;
    size_t off = 0;
    auto alloc = [&](size_t bytes) -> void* {
        void* p = ws + off;
        off += (bytes + 255) & ~(size_t)255;
        return p;
    };
    int*   flag    = (int*)alloc(sizeof(int) * 64);
    int*   ghist   = (int*)alloc(sizeof(int) * (size_t)NB * B);
    int*   goff    = (int*)alloc(sizeof(int) * (size_t)NB * B);
    int*   bsum    = (int*)alloc(sizeof(int) * B);
    int*   bbase   = (int*)alloc(sizeof(int) * (B + 1));
    int*   row_ptr = (int*)alloc(sizeof(int) * (n + 1));
    int*   col_src = (int*)alloc(sizeof(int) * (size_t)E);
    float* dinv    = (float*)alloc(sizeof(float) * n);
    unsigned short* hs1b = (unsigned short*)alloc(sizeof(unsigned short) * (size_t)n * 64);
    float* hs2     = (float*)alloc(sizeof(float) * (size_t)n * 4);
    unsigned int* ebuf = (unsigned int*)alloc(sizeof(unsigned int) * (size_t)E);
    (void)n_in; (void)out_size; (void)ws_size;

    detect_width<<<1, 64, 0, stream>>>((const unsigned int*)ei, flag);
    hist_pass<<<NB, 256, 0, stream>>>(ei, E, flag, ghist, B);
    col_scan<<<B, NB, 0, stream>>>(ghist, goff, bsum, B);
    base_scan<<<1, 512, 0, stream>>>(bsum, bbase, row_ptr, B, n, E);
    scatter_pass<<<NB, 256, 0, stream>>>(ei, E, flag, goff, bbase, ebuf, B);
    bucket_csr<<<B, 512, 0, stream>>>(ebuf, bbase, row_ptr, dinv, col_src, n);
    gemm1_kernel<<<(n + 63) / 64, 256, 0, stream>>>(x, W1, dinv, hs1b, n);
    agg1_kernel<<<(n + 3) / 4, 256, 0, stream>>>(row_ptr, col_src, hs1b, dinv, b1, W2, hs2, n);
    agg2_kernel<<<(n + 3) / 4, 256, 0, stream>>>(row_ptr, col_src, hs2, dinv, b2, (float*)d_out, n);
}

// Round 7
// 210.546 us; speedup vs baseline: 7.9698x; 1.0029x over previous
//
#include <hip/hip_runtime.h>
#include <hip/hip_bf16.h>
#include <math.h>

// ---------------------------------------------------------------------------
// GCN 2-layer forward. Pipeline (round 7):
//   detect width -> hist_pass (per-block bucket histogram) -> col_scan ->
//   base_scan -> scatter_pass (LDS counting sort per block, coalesced run
//   flush; no global atomics) -> bucket_csr (per-bucket counting sort ->
//   CSR + dinv) -> gemm1 (MFMA bf16) ->
//   agg1 (wave/node bf16 gather, 32-edge MLP loop, fused gemm2 epilogue) ->
//   agg2 (+softmax)
// Round-6 evidence: agg1 75us (epilogue chain latency; fix = deeper gather
// unroll), scatter per-thread 4B stores (fix = LDS sort + run flush).
// ---------------------------------------------------------------------------

#define NB 512     // multisplit blocks (hist & scatter must match)
#define MAXB 512   // max buckets (n <= 131072)
#define SCHUNK 6400 // scatter LDS buffer entries (>= ceil(E/NB) for E<=3.27M)

typedef __attribute__((ext_vector_type(8))) short bf16x8;
typedef __attribute__((ext_vector_type(4))) float f32x4;

__device__ __forceinline__ int edge_val(const void* ep, size_t idx, int is64) {
    if (is64) return (int)(((const long long*)ep)[idx]);
    return ((const int*)ep)[idx];
}

__device__ __forceinline__ unsigned short f2bf(float f) {  // RNE
    unsigned int u = __float_as_uint(f);
    return (unsigned short)((u + 0x7FFFu + ((u >> 16) & 1u)) >> 16);
}
__device__ __forceinline__ float bf2f(unsigned short b) {
    return __uint_as_float((unsigned int)b << 16);
}

__global__ void detect_width(const unsigned int* __restrict__ ew, int* __restrict__ flag) {
    if (threadIdx.x == 0 && blockIdx.x == 0) {
        int f = 1;
        for (int i = 0; i < 64; ++i)
            if (ew[2 * i + 1] != 0u) { f = 0; break; }
        *flag = f;
    }
}

// Pass A: per-block histogram of dst buckets (reads contiguous dst half).
__global__ __launch_bounds__(256) void hist_pass(
    const void* __restrict__ edges, int E, const int* __restrict__ flagp,
    int* __restrict__ ghist, int B) {
    __shared__ int hist[MAXB];
    const int tid = threadIdx.x;
    for (int i = tid; i < B; i += 256) hist[i] = 0;
    __syncthreads();
    const int is64 = *flagp;
    const int per = (E + NB - 1) / NB;
    const int s0 = blockIdx.x * per;
    const int s1 = min(s0 + per, E);
    for (int i = s0 + tid; i < s1; i += 256) {
        const int d = edge_val(edges, (size_t)E + i, is64);
        atomicAdd(&hist[d >> 8], 1);
    }
    __syncthreads();
    for (int i = tid; i < B; i += 256) ghist[(size_t)blockIdx.x * B + i] = hist[i];
}

// Column scan: for bucket b, exclusive scan of ghist[blk][b] over blk.
__global__ __launch_bounds__(NB) void col_scan(
    const int* __restrict__ ghist, int* __restrict__ goff,
    int* __restrict__ bsum, int B) {
    __shared__ int sm[NB];
    const int tid = threadIdx.x;
    const int b = blockIdx.x;
    const int v = ghist[(size_t)tid * B + b];
    sm[tid] = v;
    __syncthreads();
    for (int off = 1; off < NB; off <<= 1) {
        int val = (tid >= off) ? sm[tid - off] : 0;
        __syncthreads();
        sm[tid] += val;
        __syncthreads();
    }
    goff[(size_t)tid * B + b] = sm[tid] - v;
    if (tid == NB - 1) bsum[b] = sm[tid];
}

// Bucket-base exclusive scan; bbase[B] = E; row_ptr[n] = E.
__global__ __launch_bounds__(512) void base_scan(
    const int* __restrict__ bsum, int* __restrict__ bbase,
    int* __restrict__ row_ptr, int B, int n, int E) {
    __shared__ int sm[512];
    const int tid = threadIdx.x;
    const int v = (tid < B) ? bsum[tid] : 0;
    sm[tid] = v;
    __syncthreads();
    for (int off = 1; off < 512; off <<= 1) {
        int val = (tid >= off) ? sm[tid - off] : 0;
        __syncthreads();
        sm[tid] += val;
        __syncthreads();
    }
    if (tid < B) bbase[tid] = sm[tid] - v;
    if (tid == 0) { bbase[B] = E; row_ptr[n] = E; }
}

// Pass B: per-block LDS counting sort by bucket, then coalesced run flush.
// Uses precomputed per-block counts (ghist) for exact local bases. Fallback
// (per > SCHUNK, shouldn't happen at this size): direct LDS-offset scatter.
__global__ __launch_bounds__(512) void scatter_pass(
    const void* __restrict__ edges, int E, const int* __restrict__ flagp,
    const int* __restrict__ ghist, const int* __restrict__ goff,
    const int* __restrict__ bbase, unsigned int* __restrict__ ebuf, int B) {
    __shared__ unsigned int buf[SCHUNK];
    __shared__ int lb[MAXB];    // local exclusive base (preserved)
    __shared__ int lf[MAXB];    // fill cursor
    __shared__ int sm[MAXB];
    const int tid = threadIdx.x;
    const int blk = blockIdx.x;
    const int is64 = *flagp;
    const int per = (E + NB - 1) / NB;
    const int s0 = blk * per;
    const int s1 = min(s0 + per, E);

    if (per <= SCHUNK) {
        // exclusive scan of this block's bucket counts
        const int c = (tid < B) ? ghist[(size_t)blk * B + tid] : 0;
        sm[tid] = c;
        __syncthreads();
        for (int off = 1; off < MAXB; off <<= 1) {
            int val = (tid >= off) ? sm[tid - off] : 0;
            __syncthreads();
            sm[tid] += val;
            __syncthreads();
        }
        if (tid < B) { lb[tid] = sm[tid] - c; lf[tid] = sm[tid] - c; }
        __syncthreads();
        // place edges into LDS, sorted by bucket
        for (int i = s0 + tid; i < s1; i += 512) {
            const int d = edge_val(edges, (size_t)E + i, is64);
            const int s = edge_val(edges, (size_t)i, is64);
            const unsigned int val = ((unsigned int)s << 8) | (unsigned int)(d & 255);
            const int pos = atomicAdd(&lf[d >> 8], 1);
            buf[pos] = val;
        }
        __syncthreads();
        // flush runs: wave w handles buckets w, w+8, ...; lanes copy entries
        const int lane = tid & 63;
        const int wv = tid >> 6;
        for (int b = wv; b < B; b += 8) {
            const int lo = lb[b];
            const int cnt = lf[b] - lo;
            if (cnt > 0) {
                unsigned int* dst = ebuf + bbase[b] + goff[(size_t)blk * B + b];
                for (int k = lane; k < cnt; k += 64) dst[k] = buf[lo + k];
            }
        }
    } else {
        // fallback: direct scatter with LDS running offsets
        for (int i = tid; i < B; i += 512)
            lf[i] = bbase[i] + goff[(size_t)blk * B + i];
        __syncthreads();
        for (int i = s0 + tid; i < s1; i += 512) {
            const int d = edge_val(edges, (size_t)E + i, is64);
            const int s = edge_val(edges, (size_t)i, is64);
            const int pos = atomicAdd(&lf[d >> 8], 1);
            ebuf[pos] = ((unsigned int)s << 8) | (unsigned int)(d & 255);
        }
    }
}

// Per-bucket counting sort -> col_src CSR + row_ptr + dinv.
__global__ __launch_bounds__(512) void bucket_csr(
    const unsigned int* __restrict__ ebuf, const int* __restrict__ bbase,
    int* __restrict__ row_ptr, float* __restrict__ dinv,
    int* __restrict__ col_src, int n) {
    __shared__ int hist[256];
    __shared__ int scn[256];
    __shared__ int fill[256];
    const int tid = threadIdx.x;
    const int b = blockIdx.x;
    if (tid < 256) hist[tid] = 0;
    __syncthreads();
    const int base = bbase[b];
    const int m = bbase[b + 1] - base;
    const unsigned int* eb = ebuf + base;
    for (int i = tid; i < m; i += 512) atomicAdd(&hist[eb[i] & 255u], 1);
    __syncthreads();
    if (tid < 256) scn[tid] = hist[tid];
    __syncthreads();
    for (int off = 1; off < 256; off <<= 1) {
        int val = 0;
        if (tid < 256 && tid >= off) val = scn[tid - off];
        __syncthreads();
        if (tid < 256) scn[tid] += val;
        __syncthreads();
    }
    if (tid < 256) {
        const int excl = scn[tid] - hist[tid];
        fill[tid] = excl;
        const int v = b * 256 + tid;
        if (v < n) {
            row_ptr[v] = base + excl;
            dinv[v] = rsqrtf((float)hist[tid] + 1.0f);
        }
    }
    __syncthreads();
    for (int i = tid; i < m; i += 512) {
        const unsigned int e = eb[i];
        const int p = atomicAdd(&fill[e & 255u], 1);
        col_src[base + p] = (int)(e >> 8);
    }
}

// GEMM1 (MFMA): hs1b[v][c] = bf16((x@W1)[v][c] * dinv[v]),  256 -> 64.
__global__ __launch_bounds__(256) void gemm1_kernel(
    const float* __restrict__ x, const float* __restrict__ W1,
    const float* __restrict__ dinv, unsigned short* __restrict__ hs1b, int n) {
    __shared__ unsigned short wt[64 * 264];  // [col][k], 33792 B
    const int tid = threadIdx.x;
    for (int i = tid; i < 4096; i += 256) {
        const int k = i >> 4;
        const int c0 = (i & 15) * 4;
        const float4 w = *((const float4*)W1 + i);
        wt[(c0 + 0) * 264 + k] = f2bf(w.x);
        wt[(c0 + 1) * 264 + k] = f2bf(w.y);
        wt[(c0 + 2) * 264 + k] = f2bf(w.z);
        wt[(c0 + 3) * 264 + k] = f2bf(w.w);
    }
    __syncthreads();

    const int lane = tid & 63;
    const int wid = tid >> 6;
    const int row0 = blockIdx.x * 64 + wid * 16;
    const int rr = lane & 15;
    const int kh = lane >> 4;

    union FragU { bf16x8 v; unsigned short u[8]; };
    bf16x8 af[8];
    {
        int r = row0 + rr;
        if (r >= n) r = n - 1;
        const float* xr = x + (size_t)r * 256 + kh * 8;
#pragma unroll
        for (int ks = 0; ks < 8; ++ks) {
            const float4 p0 = *(const float4*)(xr + ks * 32);
            const float4 p1 = *(const float4*)(xr + ks * 32 + 4);
            FragU f;
            f.u[0] = f2bf(p0.x); f.u[1] = f2bf(p0.y);
            f.u[2] = f2bf(p0.z); f.u[3] = f2bf(p0.w);
            f.u[4] = f2bf(p1.x); f.u[5] = f2bf(p1.y);
            f.u[6] = f2bf(p1.z); f.u[7] = f2bf(p1.w);
            af[ks] = f.v;
        }
    }
    f32x4 acc[4];
#pragma unroll
    for (int ct = 0; ct < 4; ++ct) acc[ct] = (f32x4){0.f, 0.f, 0.f, 0.f};
#pragma unroll
    for (int ct = 0; ct < 4; ++ct) {
        const unsigned short* wcol = wt + (ct * 16 + rr) * 264 + kh * 8;
#pragma unroll
        for (int ks = 0; ks < 8; ++ks) {
            const bf16x8 bf = *(const bf16x8*)(wcol + ks * 32);
            acc[ct] = __builtin_amdgcn_mfma_f32_16x16x32_bf16(af[ks], bf, acc[ct], 0, 0, 0);
        }
    }
#pragma unroll
    for (int j = 0; j < 4; ++j) {
        const int gr = row0 + kh * 4 + j;
        if (gr < n) {
            const float dv = dinv[gr];
#pragma unroll
            for (int ct = 0; ct < 4; ++ct)
                hs1b[(size_t)gr * 64 + ct * 16 + rr] = f2bf(acc[ct][j] * dv);
        }
    }
}

// AGG1 + fused GEMM2: wave per node. 32-edge main loop: one coalesced
// col_src load feeds 8 independent row-gathers in flight.
__global__ __launch_bounds__(256) void agg1_kernel(
    const int* __restrict__ row_ptr, const int* __restrict__ col_src,
    const unsigned short* __restrict__ hs1b, const float* __restrict__ dinv,
    const float* __restrict__ b1, const float* __restrict__ W2,
    float* __restrict__ hs2, int n) {
    const int lane = threadIdx.x & 63;
    int v = blockIdx.x * 4 + (threadIdx.x >> 6);
    v = __builtin_amdgcn_readfirstlane(v);
    if (v >= n) return;
    const int g = lane >> 4;
    const int q = lane & 15;
    const int rs = row_ptr[v];
    const int re = row_ptr[v + 1];
    float a0 = 0.f, a1 = 0.f, a2 = 0.f, a3 = 0.f;
    float c0 = 0.f, c1 = 0.f, c2 = 0.f, c3 = 0.f;
    int e = rs;
    // 32-edge blocks: 8 gathers in flight per wave
    for (; e + 32 <= re; e += 32) {
        const int cs = col_src[e + (lane & 31)];
        const int s0 = __shfl(cs, 0 + g),  s1 = __shfl(cs, 4 + g);
        const int s2 = __shfl(cs, 8 + g),  s3 = __shfl(cs, 12 + g);
        const int s4 = __shfl(cs, 16 + g), s5 = __shfl(cs, 20 + g);
        const int s6 = __shfl(cs, 24 + g), s7 = __shfl(cs, 28 + g);
        const ushort4 r0 = *((const ushort4*)(hs1b + (size_t)s0 * 64) + q);
        const ushort4 r1 = *((const ushort4*)(hs1b + (size_t)s1 * 64) + q);
        const ushort4 r2 = *((const ushort4*)(hs1b + (size_t)s2 * 64) + q);
        const ushort4 r3 = *((const ushort4*)(hs1b + (size_t)s3 * 64) + q);
        const ushort4 r4 = *((const ushort4*)(hs1b + (size_t)s4 * 64) + q);
        const ushort4 r5 = *((const ushort4*)(hs1b + (size_t)s5 * 64) + q);
        const ushort4 r6 = *((const ushort4*)(hs1b + (size_t)s6 * 64) + q);
        const ushort4 r7 = *((const ushort4*)(hs1b + (size_t)s7 * 64) + q);
        a0 += bf2f(r0.x) + bf2f(r1.x) + bf2f(r2.x) + bf2f(r3.x);
        a1 += bf2f(r0.y) + bf2f(r1.y) + bf2f(r2.y) + bf2f(r3.y);
        a2 += bf2f(r0.z) + bf2f(r1.z) + bf2f(r2.z) + bf2f(r3.z);
        a3 += bf2f(r0.w) + bf2f(r1.w) + bf2f(r2.w) + bf2f(r3.w);
        c0 += bf2f(r4.x) + bf2f(r5.x) + bf2f(r6.x) + bf2f(r7.x);
        c1 += bf2f(r4.y) + bf2f(r5.y) + bf2f(r6.y) + bf2f(r7.y);
        c2 += bf2f(r4.z) + bf2f(r5.z) + bf2f(r6.z) + bf2f(r7.z);
        c3 += bf2f(r4.w) + bf2f(r5.w) + bf2f(r6.w) + bf2f(r7.w);
    }
    a0 += c0; a1 += c1; a2 += c2; a3 += c3;
    // 16-edge block
    for (; e + 16 <= re; e += 16) {
        const int cs = col_src[e + q];
        const int s0 = __shfl(cs, 0 + g);
        const int s1 = __shfl(cs, 4 + g);
        const int s2 = __shfl(cs, 8 + g);
        const int s3 = __shfl(cs, 12 + g);
        const ushort4 r0 = *((const ushort4*)(hs1b + (size_t)s0 * 64) + q);
        const ushort4 r1 = *((const ushort4*)(hs1b + (size_t)s1 * 64) + q);
        const ushort4 r2 = *((const ushort4*)(hs1b + (size_t)s2 * 64) + q);
        const ushort4 r3 = *((const ushort4*)(hs1b + (size_t)s3 * 64) + q);
        a0 += bf2f(r0.x) + bf2f(r1.x) + bf2f(r2.x) + bf2f(r3.x);
        a1 += bf2f(r0.y) + bf2f(r1.y) + bf2f(r2.y) + bf2f(r3.y);
        a2 += bf2f(r0.z) + bf2f(r1.z) + bf2f(r2.z) + bf2f(r3.z);
        a3 += bf2f(r0.w) + bf2f(r1.w) + bf2f(r2.w) + bf2f(r3.w);
    }
    // tail: 4 edges / step
    for (; e < re; e += 4) {
        if (e + g < re) {
            const int s = col_src[e + g];
            const ushort4 r = *((const ushort4*)(hs1b + (size_t)s * 64) + q);
            a0 += bf2f(r.x); a1 += bf2f(r.y); a2 += bf2f(r.z); a3 += bf2f(r.w);
        }
    }
    a0 += __shfl_xor(a0, 16); a1 += __shfl_xor(a1, 16);
    a2 += __shfl_xor(a2, 16); a3 += __shfl_xor(a3, 16);
    a0 += __shfl_xor(a0, 32); a1 += __shfl_xor(a1, 32);
    a2 += __shfl_xor(a2, 32); a3 += __shfl_xor(a3, 32);
    const ushort4 sr = *((const ushort4*)(hs1b + (size_t)v * 64) + q);
    const float dv = dinv[v];
    const float4 bb = *((const float4*)b1 + q);
    float4 res;
    res.x = dv * (a0 + bf2f(sr.x)) + bb.x;
    res.y = dv * (a1 + bf2f(sr.y)) + bb.y;
    res.z = dv * (a2 + bf2f(sr.z)) + bb.z;
    res.w = dv * (a3 + bf2f(sr.w)) + bb.w;
    res.x = res.x > 0.f ? res.x : 0.01f * res.x;
    res.y = res.y > 0.f ? res.y : 0.01f * res.y;
    res.z = res.z > 0.f ? res.z : 0.01f * res.z;
    res.w = res.w > 0.f ? res.w : 0.01f * res.w;
    // fused gemm2: p = res . W2[4q..4q+3][:]; reduce over q (16 lanes)
    const float4* W2v = (const float4*)W2;
    const float4 w0 = W2v[q * 4 + 0], w1 = W2v[q * 4 + 1];
    const float4 w2 = W2v[q * 4 + 2], w3 = W2v[q * 4 + 3];
    float4 p;
    p.x = res.x * w0.x + res.y * w1.x + res.z * w2.x + res.w * w3.x;
    p.y = res.x * w0.y + res.y * w1.y + res.z * w2.y + res.w * w3.y;
    p.z = res.x * w0.z + res.y * w1.z + res.z * w2.z + res.w * w3.z;
    p.w = res.x * w0.w + res.y * w1.w + res.z * w2.w + res.w * w3.w;
#pragma unroll
    for (int s = 1; s < 16; s <<= 1) {
        p.x += __shfl_xor(p.x, s); p.y += __shfl_xor(p.y, s);
        p.z += __shfl_xor(p.z, s); p.w += __shfl_xor(p.w, s);
    }
    if (lane == 0) {
        float4 o; o.x = p.x * dv; o.y = p.y * dv; o.z = p.z * dv; o.w = p.w * dv;
        *(float4*)(hs2 + (size_t)v * 4) = o;
    }
}

// AGG2 + softmax: wave per node; lane -> (edge slot = lane>>2, col = lane&3)
__global__ __launch_bounds__(256) void agg2_kernel(
    const int* __restrict__ row_ptr, const int* __restrict__ col_src,
    const float* __restrict__ hs2, const float* __restrict__ dinv,
    const float* __restrict__ b2, float* __restrict__ out, int n) {
    const int lane = threadIdx.x & 63;
    int v = blockIdx.x * 4 + (threadIdx.x >> 6);
    v = __builtin_amdgcn_readfirstlane(v);
    if (v >= n) return;
    const int c = lane & 3;
    const int ei = lane >> 2;
    const int rs = row_ptr[v];
    const int re = row_ptr[v + 1];
    float acc = 0.f;
    for (int e0 = rs; e0 < re; e0 += 16) {
        const int e = e0 + ei;
        if (e < re) {
            const int s = col_src[e];
            acc += hs2[(size_t)s * 4 + c];
        }
    }
    acc += __shfl_xor(acc, 4);
    acc += __shfl_xor(acc, 8);
    acc += __shfl_xor(acc, 16);
    acc += __shfl_xor(acc, 32);
    const float val = dinv[v] * (acc + hs2[(size_t)v * 4 + c]) + b2[c];
    float m = fmaxf(val, __shfl_xor(val, 1));
    m = fmaxf(m, __shfl_xor(m, 2));
    const float ex = __expf(val - m);
    float s = ex + __shfl_xor(ex, 1);
    s += __shfl_xor(s, 2);
    if (lane < 4) out[(size_t)v * 4 + c] = ex / s;
}

extern "C" void kernel_launch(void* const* d_in, const int* in_sizes, int n_in,
                              void* d_out, int out_size, void* d_ws, size_t ws_size,
                              hipStream_t stream) {
    const float* x  = (const float*)d_in[0];
    const void*  ei = d_in[1];
    const float* W1 = (const float*)d_in[2];
    const float* b1 = (const float*)d_in[3];
    const float* W2 = (const float*)d_in[4];
    const float* b2 = (const float*)d_in[5];
    const int n = in_sizes[0] / 256;
    const int E = in_sizes[1] / 2;
    const int B = (n + 255) / 256;  // <= MAXB for n <= 131072

    char* ws = (char*)d_ws;
    size_t off = 0;
    auto alloc = [&](size_t bytes) -> void* {
        void* p = ws + off;
        off += (bytes + 255) & ~(size_t)255;
        return p;
    };
    int*   flag    = (int*)alloc(sizeof(int) * 64);
    int*   ghist   = (int*)alloc(sizeof(int) * (size_t)NB * B);
    int*   goff    = (int*)alloc(sizeof(int) * (size_t)NB * B);
    int*   bsum    = (int*)alloc(sizeof(int) * B);
    int*   bbase   = (int*)alloc(sizeof(int) * (B + 1));
    int*   row_ptr = (int*)alloc(sizeof(int) * (n + 1));
    int*   col_src = (int*)alloc(sizeof(int) * (size_t)E);
    float* dinv    = (float*)alloc(sizeof(float) * n);
    unsigned short* hs1b = (unsigned short*)alloc(sizeof(unsigned short) * (size_t)n * 64);
    float* hs2     = (float*)alloc(sizeof(float) * (size_t)n * 4);
    unsigned int* ebuf = (unsigned int*)alloc(sizeof(unsigned int) * (size_t)E);
    (void)n_in; (void)out_size; (void)ws_size;

    detect_width<<<1, 64, 0, stream>>>((const unsigned int*)ei, flag);
    hist_pass<<<NB, 256, 0, stream>>>(ei, E, flag, ghist, B);
    col_scan<<<B, NB, 0, stream>>>(ghist, goff, bsum, B);
    base_scan<<<1, 512, 0, stream>>>(bsum, bbase, row_ptr, B, n, E);
    scatter_pass<<<NB, 512, 0, stream>>>(ei, E, flag, ghist, goff, bbase, ebuf, B);
    bucket_csr<<<B, 512, 0, stream>>>(ebuf, bbase, row_ptr, dinv, col_src, n);
    gemm1_kernel<<<(n + 63) / 64, 256, 0, stream>>>(x, W1, dinv, hs1b, n);
    agg1_kernel<<<(n + 3) / 4, 256, 0, stream>>>(row_ptr, col_src, hs1b, dinv, b1, W2, hs2, n);
    agg2_kernel<<<(n + 3) / 4, 256, 0, stream>>>(row_ptr, col_src, hs2, dinv, b2, (float*)d_out, n);
}

// Round 8
// 188.167 us; speedup vs baseline: 8.9177x; 1.1189x over previous
//
#include <hip/hip_runtime.h>
#include <hip/hip_bf16.h>
#include <math.h>

// ---------------------------------------------------------------------------
// GCN 2-layer forward. Pipeline (round 8):
//   detect width -> hist_pass -> col_scan -> base_scan -> scatter_pass (LDS
//   counting sort, coalesced flush) -> bucket_csr (-> CSR + dinv) ->
//   gemm1 (MFMA bf16, FP8 e4m3 output) ->
//   agg1 (16-lane group per node, fp8 gather + fused gemm2) -> agg2 (+softmax)
// Round-7 evidence: agg1 bandwidth-bound (dur == FETCH/2.2TB/s, unroll was
// neutral). fp8 halves row bytes (128->64B) and table (12.8->6.4MB ~ L2).
// Error budget: ~3e-4 added at output vs 5.6e-3 threshold.
// ---------------------------------------------------------------------------

#define NB 256      // multisplit blocks (hist & scatter must match)
#define MAXB 512    // max buckets (n <= 131072)
#define SCHUNK 12544 // scatter LDS entries (>= ceil(E/NB) for E<=3.21M)

typedef __attribute__((ext_vector_type(8))) short bf16x8;
typedef __attribute__((ext_vector_type(4))) float f32x4;
typedef __attribute__((ext_vector_type(2))) float f32x2;

__device__ __forceinline__ int edge_val(const void* ep, size_t idx, int is64) {
    if (is64) return (int)(((const long long*)ep)[idx]);
    return ((const int*)ep)[idx];
}

__device__ __forceinline__ unsigned short f2bf(float f) {  // RNE
    unsigned int u = __float_as_uint(f);
    return (unsigned short)((u + 0x7FFFu + ((u >> 16) & 1u)) >> 16);
}

// fp8 e4m3 (OCP) decode of a 4-byte group via HW cvt
__device__ __forceinline__ void acc_fp8row(unsigned int r, float& a0, float& a1,
                                           float& a2, float& a3) {
    const f32x2 lo = __builtin_amdgcn_cvt_pk_f32_fp8((int)r, false);
    const f32x2 hi = __builtin_amdgcn_cvt_pk_f32_fp8((int)r, true);
    a0 += lo[0]; a1 += lo[1]; a2 += hi[0]; a3 += hi[1];
}

__device__ __forceinline__ unsigned char f32_to_fp8(float f) {
    const int enc = __builtin_amdgcn_cvt_pk_fp8_f32(f, 0.f, 0, false);
    return (unsigned char)(enc & 0xff);
}

__global__ void detect_width(const unsigned int* __restrict__ ew, int* __restrict__ flag) {
    const int i = threadIdx.x;
    const unsigned long long m = __ballot(ew[2 * i + 1] != 0u);
    if (i == 0) *flag = (m == 0ull) ? 1 : 0;
}

// Pass A: per-block histogram of dst buckets.
__global__ __launch_bounds__(256) void hist_pass(
    const void* __restrict__ edges, int E, const int* __restrict__ flagp,
    int* __restrict__ ghist, int B) {
    __shared__ int hist[MAXB];
    const int tid = threadIdx.x;
    for (int i = tid; i < B; i += 256) hist[i] = 0;
    __syncthreads();
    const int is64 = *flagp;
    const int per = (E + NB - 1) / NB;
    const int s0 = blockIdx.x * per;
    const int s1 = min(s0 + per, E);
    for (int i = s0 + tid; i < s1; i += 256) {
        const int d = edge_val(edges, (size_t)E + i, is64);
        atomicAdd(&hist[d >> 8], 1);
    }
    __syncthreads();
    for (int i = tid; i < B; i += 256) ghist[(size_t)blockIdx.x * B + i] = hist[i];
}

// Column scan: for bucket b, exclusive scan of ghist[blk][b] over blk.
__global__ __launch_bounds__(NB) void col_scan(
    const int* __restrict__ ghist, int* __restrict__ goff,
    int* __restrict__ bsum, int B) {
    __shared__ int sm[NB];
    const int tid = threadIdx.x;
    const int b = blockIdx.x;
    const int v = ghist[(size_t)tid * B + b];
    sm[tid] = v;
    __syncthreads();
    for (int off = 1; off < NB; off <<= 1) {
        int val = (tid >= off) ? sm[tid - off] : 0;
        __syncthreads();
        sm[tid] += val;
        __syncthreads();
    }
    goff[(size_t)tid * B + b] = sm[tid] - v;
    if (tid == NB - 1) bsum[b] = sm[tid];
}

// Bucket-base exclusive scan; bbase[B] = E; row_ptr[n] = E.
__global__ __launch_bounds__(512) void base_scan(
    const int* __restrict__ bsum, int* __restrict__ bbase,
    int* __restrict__ row_ptr, int B, int n, int E) {
    __shared__ int sm[512];
    const int tid = threadIdx.x;
    const int v = (tid < B) ? bsum[tid] : 0;
    sm[tid] = v;
    __syncthreads();
    for (int off = 1; off < 512; off <<= 1) {
        int val = (tid >= off) ? sm[tid - off] : 0;
        __syncthreads();
        sm[tid] += val;
        __syncthreads();
    }
    if (tid < B) bbase[tid] = sm[tid] - v;
    if (tid == 0) { bbase[B] = E; row_ptr[n] = E; }
}

// Pass B: per-block LDS counting sort by bucket, coalesced run flush.
__global__ __launch_bounds__(512) void scatter_pass(
    const void* __restrict__ edges, int E, const int* __restrict__ flagp,
    const int* __restrict__ ghist, const int* __restrict__ goff,
    const int* __restrict__ bbase, unsigned int* __restrict__ ebuf, int B) {
    __shared__ unsigned int buf[SCHUNK];
    __shared__ int lb[MAXB];
    __shared__ int lf[MAXB];
    __shared__ int sm[MAXB];
    const int tid = threadIdx.x;
    const int blk = blockIdx.x;
    const int is64 = *flagp;
    const int per = (E + NB - 1) / NB;
    const int s0 = blk * per;
    const int s1 = min(s0 + per, E);

    if (per <= SCHUNK) {
        const int c = (tid < B) ? ghist[(size_t)blk * B + tid] : 0;
        sm[tid] = c;
        __syncthreads();
        for (int off = 1; off < MAXB; off <<= 1) {
            int val = (tid >= off) ? sm[tid - off] : 0;
            __syncthreads();
            sm[tid] += val;
            __syncthreads();
        }
        if (tid < B) { lb[tid] = sm[tid] - c; lf[tid] = sm[tid] - c; }
        __syncthreads();
        for (int i = s0 + tid; i < s1; i += 512) {
            const int d = edge_val(edges, (size_t)E + i, is64);
            const int s = edge_val(edges, (size_t)i, is64);
            const unsigned int val = ((unsigned int)s << 8) | (unsigned int)(d & 255);
            const int pos = atomicAdd(&lf[d >> 8], 1);
            buf[pos] = val;
        }
        __syncthreads();
        const int lane = tid & 63;
        const int wv = tid >> 6;
        for (int b = wv; b < B; b += 8) {
            const int lo = lb[b];
            const int cnt = lf[b] - lo;
            if (cnt > 0) {
                unsigned int* dst = ebuf + bbase[b] + goff[(size_t)blk * B + b];
                for (int k = lane; k < cnt; k += 64) dst[k] = buf[lo + k];
            }
        }
    } else {
        for (int i = tid; i < B; i += 512)
            lf[i] = bbase[i] + goff[(size_t)blk * B + i];
        __syncthreads();
        for (int i = s0 + tid; i < s1; i += 512) {
            const int d = edge_val(edges, (size_t)E + i, is64);
            const int s = edge_val(edges, (size_t)i, is64);
            const int pos = atomicAdd(&lf[d >> 8], 1);
            ebuf[pos] = ((unsigned int)s << 8) | (unsigned int)(d & 255);
        }
    }
}

// Per-bucket counting sort -> col_src CSR + row_ptr + dinv.
__global__ __launch_bounds__(512) void bucket_csr(
    const unsigned int* __restrict__ ebuf, const int* __restrict__ bbase,
    int* __restrict__ row_ptr, float* __restrict__ dinv,
    int* __restrict__ col_src, int n) {
    __shared__ int hist[256];
    __shared__ int scn[256];
    __shared__ int fill[256];
    const int tid = threadIdx.x;
    const int b = blockIdx.x;
    if (tid < 256) hist[tid] = 0;
    __syncthreads();
    const int base = bbase[b];
    const int m = bbase[b + 1] - base;
    const unsigned int* eb = ebuf + base;
    for (int i = tid; i < m; i += 512) atomicAdd(&hist[eb[i] & 255u], 1);
    __syncthreads();
    if (tid < 256) scn[tid] = hist[tid];
    __syncthreads();
    for (int off = 1; off < 256; off <<= 1) {
        int val = 0;
        if (tid < 256 && tid >= off) val = scn[tid - off];
        __syncthreads();
        if (tid < 256) scn[tid] += val;
        __syncthreads();
    }
    if (tid < 256) {
        const int excl = scn[tid] - hist[tid];
        fill[tid] = excl;
        const int v = b * 256 + tid;
        if (v < n) {
            row_ptr[v] = base + excl;
            dinv[v] = rsqrtf((float)hist[tid] + 1.0f);
        }
    }
    __syncthreads();
    for (int i = tid; i < m; i += 512) {
        const unsigned int e = eb[i];
        const int p = atomicAdd(&fill[e & 255u], 1);
        col_src[base + p] = (int)(e >> 8);
    }
}

// GEMM1 (MFMA): hs1f8[v][c] = fp8((x@W1)[v][c] * dinv[v]),  256 -> 64.
__global__ __launch_bounds__(256) void gemm1_kernel(
    const float* __restrict__ x, const float* __restrict__ W1,
    const float* __restrict__ dinv, unsigned char* __restrict__ hs1f8, int n) {
    __shared__ unsigned short wt[64 * 264];  // [col][k], 33792 B
    const int tid = threadIdx.x;
    for (int i = tid; i < 4096; i += 256) {
        const int k = i >> 4;
        const int c0 = (i & 15) * 4;
        const float4 w = *((const float4*)W1 + i);
        wt[(c0 + 0) * 264 + k] = f2bf(w.x);
        wt[(c0 + 1) * 264 + k] = f2bf(w.y);
        wt[(c0 + 2) * 264 + k] = f2bf(w.z);
        wt[(c0 + 3) * 264 + k] = f2bf(w.w);
    }
    __syncthreads();

    const int lane = tid & 63;
    const int wid = tid >> 6;
    const int row0 = blockIdx.x * 64 + wid * 16;
    const int rr = lane & 15;
    const int kh = lane >> 4;

    union FragU { bf16x8 v; unsigned short u[8]; };
    bf16x8 af[8];
    {
        int r = row0 + rr;
        if (r >= n) r = n - 1;
        const float* xr = x + (size_t)r * 256 + kh * 8;
#pragma unroll
        for (int ks = 0; ks < 8; ++ks) {
            const float4 p0 = *(const float4*)(xr + ks * 32);
            const float4 p1 = *(const float4*)(xr + ks * 32 + 4);
            FragU f;
            f.u[0] = f2bf(p0.x); f.u[1] = f2bf(p0.y);
            f.u[2] = f2bf(p0.z); f.u[3] = f2bf(p0.w);
            f.u[4] = f2bf(p1.x); f.u[5] = f2bf(p1.y);
            f.u[6] = f2bf(p1.z); f.u[7] = f2bf(p1.w);
            af[ks] = f.v;
        }
    }
    f32x4 acc[4];
#pragma unroll
    for (int ct = 0; ct < 4; ++ct) acc[ct] = (f32x4){0.f, 0.f, 0.f, 0.f};
#pragma unroll
    for (int ct = 0; ct < 4; ++ct) {
        const unsigned short* wcol = wt + (ct * 16 + rr) * 264 + kh * 8;
#pragma unroll
        for (int ks = 0; ks < 8; ++ks) {
            const bf16x8 bf = *(const bf16x8*)(wcol + ks * 32);
            acc[ct] = __builtin_amdgcn_mfma_f32_16x16x32_bf16(af[ks], bf, acc[ct], 0, 0, 0);
        }
    }
#pragma unroll
    for (int j = 0; j < 4; ++j) {
        const int gr = row0 + kh * 4 + j;
        if (gr < n) {
            const float dv = dinv[gr];
#pragma unroll
            for (int ct = 0; ct < 4; ++ct)
                hs1f8[(size_t)gr * 64 + ct * 16 + rr] = f32_to_fp8(acc[ct][j] * dv);
        }
    }
}

// AGG1 + fused GEMM2: 16-lane group per node (4 nodes/wave). Lane q loads
// 4 fp8 cols (4B) -> 16 lanes cover a full 64B row; 16 rows in flight per
// group step. Width-16 shfl reduce for the fused res@W2.
__global__ __launch_bounds__(256) void agg1_kernel(
    const int* __restrict__ row_ptr, const int* __restrict__ col_src,
    const unsigned char* __restrict__ hs1f8, const float* __restrict__ dinv,
    const float* __restrict__ b1, const float* __restrict__ W2,
    float* __restrict__ hs2, int n) {
    const int tid = threadIdx.x;
    const int q = tid & 15;
    const int v = blockIdx.x * 16 + (tid >> 4);
    if (v >= n) return;
    const int rs = row_ptr[v];
    const int re = row_ptr[v + 1];
    float a0 = 0.f, a1 = 0.f, a2 = 0.f, a3 = 0.f;
    int e = rs;
    for (; e + 16 <= re; e += 16) {
        const int cs = col_src[e + q];
        unsigned int r[16];
#pragma unroll
        for (int j = 0; j < 16; ++j) {
            const int s = __shfl(cs, j, 16);
            r[j] = *(const unsigned int*)(hs1f8 + (size_t)s * 64 + q * 4);
        }
#pragma unroll
        for (int j = 0; j < 16; ++j) acc_fp8row(r[j], a0, a1, a2, a3);
    }
    const int rem = re - e;
    if (rem > 0) {
        const int cs = col_src[(q < rem) ? e + q : re - 1];
        for (int j = 0; j < rem; ++j) {
            const int s = __shfl(cs, j, 16);
            const unsigned int r = *(const unsigned int*)(hs1f8 + (size_t)s * 64 + q * 4);
            acc_fp8row(r, a0, a1, a2, a3);
        }
    }
    // self-term + bias + leaky
    float s0 = 0.f, s1 = 0.f, s2 = 0.f, s3 = 0.f;
    acc_fp8row(*(const unsigned int*)(hs1f8 + (size_t)v * 64 + q * 4), s0, s1, s2, s3);
    const float dv = dinv[v];
    const float4 bb = ((const float4*)b1)[q];
    float4 res;
    res.x = dv * (a0 + s0) + bb.x;
    res.y = dv * (a1 + s1) + bb.y;
    res.z = dv * (a2 + s2) + bb.z;
    res.w = dv * (a3 + s3) + bb.w;
    res.x = res.x > 0.f ? res.x : 0.01f * res.x;
    res.y = res.y > 0.f ? res.y : 0.01f * res.y;
    res.z = res.z > 0.f ? res.z : 0.01f * res.z;
    res.w = res.w > 0.f ? res.w : 0.01f * res.w;
    // fused gemm2: p = res . W2[4q..4q+3][:]; reduce over the 16 q-lanes
    const float4* W2v = (const float4*)W2;
    const float4 w0 = W2v[q * 4 + 0], w1 = W2v[q * 4 + 1];
    const float4 w2 = W2v[q * 4 + 2], w3 = W2v[q * 4 + 3];
    float4 p;
    p.x = res.x * w0.x + res.y * w1.x + res.z * w2.x + res.w * w3.x;
    p.y = res.x * w0.y + res.y * w1.y + res.z * w2.y + res.w * w3.y;
    p.z = res.x * w0.z + res.y * w1.z + res.z * w2.z + res.w * w3.z;
    p.w = res.x * w0.w + res.y * w1.w + res.z * w2.w + res.w * w3.w;
#pragma unroll
    for (int s = 1; s < 16; s <<= 1) {
        p.x += __shfl_xor(p.x, s, 16); p.y += __shfl_xor(p.y, s, 16);
        p.z += __shfl_xor(p.z, s, 16); p.w += __shfl_xor(p.w, s, 16);
    }
    if (q == 0) {
        float4 o; o.x = p.x * dv; o.y = p.y * dv; o.z = p.z * dv; o.w = p.w * dv;
        *(float4*)(hs2 + (size_t)v * 4) = o;
    }
}

// AGG2 + softmax: wave per node; lane -> (edge slot = lane>>2, col = lane&3)
__global__ __launch_bounds__(256) void agg2_kernel(
    const int* __restrict__ row_ptr, const int* __restrict__ col_src,
    const float* __restrict__ hs2, const float* __restrict__ dinv,
    const float* __restrict__ b2, float* __restrict__ out, int n) {
    const int lane = threadIdx.x & 63;
    int v = blockIdx.x * 4 + (threadIdx.x >> 6);
    v = __builtin_amdgcn_readfirstlane(v);
    if (v >= n) return;
    const int c = lane & 3;
    const int ei = lane >> 2;
    const int rs = row_ptr[v];
    const int re = row_ptr[v + 1];
    float acc = 0.f;
    for (int e0 = rs; e0 < re; e0 += 16) {
        const int e = e0 + ei;
        if (e < re) {
            const int s = col_src[e];
            acc += hs2[(size_t)s * 4 + c];
        }
    }
    acc += __shfl_xor(acc, 4);
    acc += __shfl_xor(acc, 8);
    acc += __shfl_xor(acc, 16);
    acc += __shfl_xor(acc, 32);
    const float val = dinv[v] * (acc + hs2[(size_t)v * 4 + c]) + b2[c];
    float m = fmaxf(val, __shfl_xor(val, 1));
    m = fmaxf(m, __shfl_xor(m, 2));
    const float ex = __expf(val - m);
    float s = ex + __shfl_xor(ex, 1);
    s += __shfl_xor(s, 2);
    if (lane < 4) out[(size_t)v * 4 + c] = ex / s;
}

extern "C" void kernel_launch(void* const* d_in, const int* in_sizes, int n_in,
                              void* d_out, int out_size, void* d_ws, size_t ws_size,
                              hipStream_t stream) {
    const float* x  = (const float*)d_in[0];
    const void*  ei = d_in[1];
    const float* W1 = (const float*)d_in[2];
    const float* b1 = (const float*)d_in[3];
    const float* W2 = (const float*)d_in[4];
    const float* b2 = (const float*)d_in[5];
    const int n = in_sizes[0] / 256;
    const int E = in_sizes[1] / 2;
    const int B = (n + 255) / 256;  // <= MAXB for n <= 131072

    char* ws = (char*)d_ws;
    size_t off = 0;
    auto alloc = [&](size_t bytes) -> void* {
        void* p = ws + off;
        off += (bytes + 255) & ~(size_t)255;
        return p;
    };
    int*   flag    = (int*)alloc(sizeof(int) * 64);
    int*   ghist   = (int*)alloc(sizeof(int) * (size_t)NB * B);
    int*   goff    = (int*)alloc(sizeof(int) * (size_t)NB * B);
    int*   bsum    = (int*)alloc(sizeof(int) * B);
    int*   bbase   = (int*)alloc(sizeof(int) * (B + 1));
    int*   row_ptr = (int*)alloc(sizeof(int) * (n + 1));
    int*   col_src = (int*)alloc(sizeof(int) * (size_t)E);
    float* dinv    = (float*)alloc(sizeof(float) * n);
    unsigned char* hs1f8 = (unsigned char*)alloc(sizeof(unsigned char) * (size_t)n * 64);
    float* hs2     = (float*)alloc(sizeof(float) * (size_t)n * 4);
    unsigned int* ebuf = (unsigned int*)alloc(sizeof(unsigned int) * (size_t)E);
    (void)n_in; (void)out_size; (void)ws_size;

    detect_width<<<1, 64, 0, stream>>>((const unsigned int*)ei, flag);
    hist_pass<<<NB, 256, 0, stream>>>(ei, E, flag, ghist, B);
    col_scan<<<B, NB, 0, stream>>>(ghist, goff, bsum, B);
    base_scan<<<1, 512, 0, stream>>>(bsum, bbase, row_ptr, B, n, E);
    scatter_pass<<<NB, 512, 0, stream>>>(ei, E, flag, ghist, goff, bbase, ebuf, B);
    bucket_csr<<<B, 512, 0, stream>>>(ebuf, bbase, row_ptr, dinv, col_src, n);
    gemm1_kernel<<<(n + 63) / 64, 256, 0, stream>>>(x, W1, dinv, hs1f8, n);
    agg1_kernel<<<(n + 15) / 16, 256, 0, stream>>>(row_ptr, col_src, hs1f8, dinv, b1, W2, hs2, n);
    agg2_kernel<<<(n + 3) / 4, 256, 0, stream>>>(row_ptr, col_src, hs2, dinv, b2, (float*)d_out, n);
}